// Round 11
// baseline (584.042 us; speedup 1.0000x reference)
//
#include <hip/hip_runtime.h>
#include <hip/hip_bf16.h>
#include <math.h>

#define B_SZ 1024
#define S_SZ 40
#define H_SZ 1024
#define DW_SZ 512
#define V_SZ 4000
#define XW (DW_SZ + H_SZ)      // 1536
#define NGL 8192               // hgl row: [hproj(1024) | gh(3072) | logits(4000) | pad(96)]

typedef __bf16 bf16x8 __attribute__((ext_vector_type(8)));
typedef float f32x4 __attribute__((ext_vector_type(4)));

__device__ __forceinline__ float fast_tanh(float x) {
    return 1.0f - 2.0f / (1.0f + __expf(2.0f * x));
}
__device__ __forceinline__ float fast_sigmoid(float x) {
    return 1.0f / (1.0f + __expf(-x));
}
__device__ __forceinline__ float bfraw2f(unsigned short u) {
    return __uint_as_float(((unsigned)u) << 16);
}
__device__ __forceinline__ ushort4 cvt4(float4 v) {
    union { ushort4 u; __hip_bfloat16 h[4]; } o;
    o.h[0] = __float2bfloat16(v.x); o.h[1] = __float2bfloat16(v.y);
    o.h[2] = __float2bfloat16(v.z); o.h[3] = __float2bfloat16(v.w);
    return o.u;
}

#define GLL16(gp, lp)                                                                \
    __builtin_amdgcn_global_load_lds((const __attribute__((address_space(1))) void*)(gp), \
                                     (__attribute__((address_space(3))) void*)(lp), 16, 0, 0)

// ========== 128x256 tile, BK=32, 3-slot counted-vmcnt pipelined GEMM, 2 blocks/CU ==========
// (reverted to round-6 version: 103-105 us, MfmaUtil ~35%, 0 bank conflicts — proven)
__global__ __launch_bounds__(256, 2) void gemm_bt_pipe128(
    const __hip_bfloat16* __restrict__ A, int lda,
    const __hip_bfloat16* __restrict__ W, int ldw,
    __hip_bfloat16* __restrict__ C, int ldc,
    int nbx, int K) {
    extern __shared__ char smem[];   // 3 * 24576 bytes
    const int tid = threadIdx.x;
    const int lane = tid & 63;
    const int wave = tid >> 6;
    const int wm = wave >> 1, wn = wave & 1;
    const int fr = lane & 15, fq = lane >> 4;

    int bid = blockIdx.x;
    { const int cpx = gridDim.x >> 3; bid = (bid & 7) * cpx + (bid >> 3); }  // XCD swizzle
    const int by = bid / nbx;
    const int bm = by * 128;
    const int bn = (bid - by * nbx) * 256;

    const int r0 = tid >> 2;
    const int s0 = (tid & 3) ^ ((tid >> 3) & 3);
    const __hip_bfloat16* gA0 = A + (size_t)(bm + r0) * lda + s0 * 8;
    const __hip_bfloat16* gA1 = A + (size_t)(bm + r0 + 64) * lda + s0 * 8;
    const __hip_bfloat16* gW0 = W + (size_t)(bn + r0) * ldw + s0 * 8;
    const __hip_bfloat16* gW1 = W + (size_t)(bn + r0 + 64) * ldw + s0 * 8;
    const __hip_bfloat16* gW2 = W + (size_t)(bn + r0 + 128) * ldw + s0 * 8;
    const __hip_bfloat16* gW3 = W + (size_t)(bn + r0 + 192) * ldw + s0 * 8;
    const int dst0 = tid * 16;

    int aoff[4], boff[8];
#pragma unroll
    for (int mi = 0; mi < 4; ++mi) {
        const int row = wm * 64 + mi * 16 + fr;
        aoff[mi] = row * 64 + ((fq ^ ((row >> 1) & 3)) << 4);
    }
#pragma unroll
    for (int ni = 0; ni < 8; ++ni) {
        const int col = wn * 128 + ni * 16 + fr;
        boff[ni] = 8192 + col * 64 + ((fq ^ ((col >> 1) & 3)) << 4);
    }

    const int NT = K >> 5;
    f32x4 acc[4][8] = {};

#define STAGE_T(t)                                                    \
    do {                                                              \
        char* sb = smem + ((t) % 3) * 24576;                          \
        const int kk = (t) << 5;                                      \
        GLL16(gA0 + kk, sb + dst0);                                   \
        GLL16(gA1 + kk, sb + dst0 + 4096);                            \
        GLL16(gW0 + kk, sb + 8192 + dst0);                            \
        GLL16(gW1 + kk, sb + 8192 + dst0 + 4096);                     \
        GLL16(gW2 + kk, sb + 8192 + dst0 + 8192);                     \
        GLL16(gW3 + kk, sb + 8192 + dst0 + 12288);                    \
    } while (0)

    STAGE_T(0);
    STAGE_T(1);
    __builtin_amdgcn_sched_barrier(0);
    asm volatile("s_waitcnt vmcnt(6)" ::: "memory");
    __builtin_amdgcn_s_barrier();
    __builtin_amdgcn_sched_barrier(0);

    for (int t = 0; t < NT; ++t) {
        const char* sb = smem + (t % 3) * 24576;
        bf16x8 af[4], bg[8];
#pragma unroll
        for (int ni = 0; ni < 8; ++ni) bg[ni] = *reinterpret_cast<const bf16x8*>(sb + boff[ni]);
#pragma unroll
        for (int mi = 0; mi < 4; ++mi) af[mi] = *reinterpret_cast<const bf16x8*>(sb + aoff[mi]);

        if (t + 2 < NT) STAGE_T(t + 2);

        __builtin_amdgcn_s_setprio(1);
#pragma unroll
        for (int mi = 0; mi < 4; ++mi)
#pragma unroll
            for (int ni = 0; ni < 8; ++ni)
                acc[mi][ni] = __builtin_amdgcn_mfma_f32_16x16x32_bf16(af[mi], bg[ni], acc[mi][ni], 0, 0, 0);
        __builtin_amdgcn_s_setprio(0);

        if (t != NT - 1) {
            __builtin_amdgcn_sched_barrier(0);
            if (t + 2 < NT) asm volatile("s_waitcnt vmcnt(6)" ::: "memory");
            else            asm volatile("s_waitcnt vmcnt(0)" ::: "memory");
            __builtin_amdgcn_s_barrier();
            __builtin_amdgcn_sched_barrier(0);
        }
    }
#undef STAGE_T

#pragma unroll
    for (int mi = 0; mi < 4; ++mi) {
        const int row0 = bm + wm * 64 + mi * 16 + fq * 4;
#pragma unroll
        for (int ni = 0; ni < 8; ++ni) {
            const int col = bn + wn * 128 + ni * 16 + fr;
#pragma unroll
            for (int r = 0; r < 4; ++r)
                C[(size_t)(row0 + r) * ldc + col] = __float2bfloat16(acc[mi][ni][r]);
        }
    }
}

// ---------------- bf16 MFMA GEMM (128x128, 2-barrier): C = A@W.T + bias [+ Cin] ----------------
template <int OB, int SWZ>
__global__ __launch_bounds__(256) void gemm_bt_mfma(
    const __hip_bfloat16* __restrict__ A, int lda,
    const __hip_bfloat16* __restrict__ W, int ldw,
    const float* __restrict__ bias,
    const __hip_bfloat16* __restrict__ Cin, int ldcin,   // optional additive input (nullptr -> 0)
    void* __restrict__ Cv, int ldc,
    int nbx, int N, int K) {
    __shared__ __align__(16) __hip_bfloat16 As[128 * 32];
    __shared__ __align__(16) __hip_bfloat16 Ws[128 * 32];
    const int tid = threadIdx.x;
    const int lane = tid & 63;
    const int wave = tid >> 6;

    int bid = blockIdx.x;
    if (SWZ) {
        const int cpx = gridDim.x >> 3;
        bid = (bid & 7) * cpx + (bid >> 3);
    }
    const int by = bid / nbx;
    const int bx = bid - by * nbx;
    const int bm = by * 128;
    const int bn = bx * 128;

    const int r0 = tid >> 2;
    const int kk = (tid & 3) * 8;
    const __hip_bfloat16* gA0 = A + (size_t)(bm + r0) * lda + kk;
    const __hip_bfloat16* gA1 = gA0 + (size_t)64 * lda;
    int wrow0 = bn + r0;      if (wrow0 > N - 1) wrow0 = N - 1;
    int wrow1 = bn + r0 + 64; if (wrow1 > N - 1) wrow1 = N - 1;
    const __hip_bfloat16* gW0 = W + (size_t)wrow0 * ldw + kk;
    const __hip_bfloat16* gW1 = W + (size_t)wrow1 * ldw + kk;
    char* As_c = (char*)As + tid * 16;
    char* Ws_c = (char*)Ws + tid * 16;

    const int wr = wave >> 1, wc = wave & 1;
    const int fr = lane & 15, fq = lane >> 4;
    const __hip_bfloat16* Ard = &As[(wr * 64 + fr) * 32 + fq * 8];
    const __hip_bfloat16* Wrd = &Ws[(wc * 64 + fr) * 32 + fq * 8];

    f32x4 acc[4][4] = {};

    for (int k0 = 0; k0 < K; k0 += 32) {
        __syncthreads();
        GLL16(gA0 + k0, As_c);
        GLL16(gA1 + k0, As_c + 4096);
        GLL16(gW0 + k0, Ws_c);
        GLL16(gW1 + k0, Ws_c + 4096);
        __syncthreads();

        bf16x8 af[4], bg[4];
#pragma unroll
        for (int i = 0; i < 4; ++i) {
            af[i] = *reinterpret_cast<const bf16x8*>(Ard + i * 16 * 32);
            bg[i] = *reinterpret_cast<const bf16x8*>(Wrd + i * 16 * 32);
        }
#pragma unroll
        for (int mi = 0; mi < 4; ++mi)
#pragma unroll
            for (int ni = 0; ni < 4; ++ni)
                acc[mi][ni] = __builtin_amdgcn_mfma_f32_16x16x32_bf16(af[mi], bg[ni], acc[mi][ni], 0, 0, 0);
    }

#pragma unroll
    for (int ni = 0; ni < 4; ++ni) {
        const int col = bn + wc * 64 + ni * 16 + fr;
        if (col >= N) continue;
        const float bb = bias ? bias[col] : 0.0f;
#pragma unroll
        for (int mi = 0; mi < 4; ++mi) {
            const int row0 = bm + wr * 64 + mi * 16 + fq * 4;
#pragma unroll
            for (int r = 0; r < 4; ++r) {
                float v = acc[mi][ni][r] + bb;
                if (Cin)
                    v += bfraw2f(reinterpret_cast<const unsigned short*>(Cin)[(size_t)(row0 + r) * ldcin + col]);
                if (OB)
                    reinterpret_cast<__hip_bfloat16*>(Cv)[(size_t)(row0 + r) * ldc + col] = __float2bfloat16(v);
                else
                    reinterpret_cast<float*>(Cv)[(size_t)(row0 + r) * ldc + col] = v;
            }
        }
    }
}

// ---------------- fast cast: compile-time segments, 4-way ILP ----------------
#define F4_ENC (B_SZ * S_SZ * H_SZ / 4)
#define F4_W1A (H_SZ * H_SZ / 4)
#define F4_W1H (H_SZ * H_SZ / 4)
#define F4_WHH (3 * H_SZ * H_SZ / 4)
#define F4_WIH (3 * H_SZ * XW / 4)
#define F4_O0  (V_SZ * H_SZ / 4)
#define F4_O1  (V_SZ * H_SZ / 4)
#define CE0 (F4_ENC)
#define CE1 (CE0 + F4_W1A)
#define CE2 (CE1 + F4_W1H)
#define CE3 (CE2 + F4_WHH)
#define CE4 (CE3 + F4_WIH)
#define CE5 (CE4 + F4_O0)
#define CE6 (CE5 + F4_O1)                  // total 15024128 = 14672 * 1024
__global__ __launch_bounds__(256) void cast_fast_kernel(
    const float* __restrict__ enc, const float* __restrict__ w1,
    const float* __restrict__ whh, const float* __restrict__ wih,
    const float* __restrict__ o0, const float* __restrict__ o1,
    __hip_bfloat16* __restrict__ enc_bf, __hip_bfloat16* __restrict__ w1a_bf,
    __hip_bfloat16* __restrict__ wall0, __hip_bfloat16* __restrict__ wall1,
    __hip_bfloat16* __restrict__ wih_bf) {
    ushort4* wall0_u = reinterpret_cast<ushort4*>(wall0);
    ushort4* wall1_u = reinterpret_cast<ushort4*>(wall1);
    const int base = blockIdx.x * 1024 + threadIdx.x;
#pragma unroll
    for (int k = 0; k < 4; ++k) {
        const int i = base + k * 256;   // 4 independent chains per thread
        if (i < CE0) {
            reinterpret_cast<ushort4*>(enc_bf)[i] = cvt4(reinterpret_cast<const float4*>(enc)[i]);
        } else if (i < CE1) {
            const int li = i - CE0;
            const int r = li >> 8, c = li & 255;
            reinterpret_cast<ushort4*>(w1a_bf)[li] = cvt4(reinterpret_cast<const float4*>(w1)[r * 512 + c]);
        } else if (i < CE2) {
            const int li = i - CE1;
            const int r = li >> 8, c = li & 255;
            const ushort4 u = cvt4(reinterpret_cast<const float4*>(w1)[r * 512 + 256 + c]);
            wall0_u[li] = u;
            wall1_u[li] = u;
        } else if (i < CE3) {
            const int li = i - CE2;
            const ushort4 u = cvt4(reinterpret_cast<const float4*>(whh)[li]);
            wall0_u[262144 + li] = u;
            wall1_u[262144 + li] = u;
        } else if (i < CE4) {
            const int li = i - CE3;
            reinterpret_cast<ushort4*>(wih_bf)[li] = cvt4(reinterpret_cast<const float4*>(wih)[li]);
        } else if (i < CE5) {
            const int li = i - CE4;
            wall0_u[1048576 + li] = cvt4(reinterpret_cast<const float4*>(o0)[li]);
        } else {
            const int li = i - CE5;
            wall1_u[1048576 + li] = cvt4(reinterpret_cast<const float4*>(o1)[li]);
        }
    }
}

// ---------------- small prep: emb prefill (<3072), h init (3072..4095), bias0/bias1 (4096/4097) ----------------
__global__ __launch_bounds__(256) void small_prep_kernel(
    const float* __restrict__ emb, const int* __restrict__ targets,
    __hip_bfloat16* __restrict__ x0, __hip_bfloat16* __restrict__ x1, __hip_bfloat16* __restrict__ x2,
    const float* __restrict__ enc_h, float* __restrict__ h, __hip_bfloat16* __restrict__ h_bf,
    const float* __restrict__ b1, const float* __restrict__ b_hh,
    const float* __restrict__ o0b, const float* __restrict__ o1b,
    float* __restrict__ bias0, float* __restrict__ bias1) {
    const int blk = blockIdx.x;
    const int tid = threadIdx.x;
    if (blk < 3072) {
        if (tid >= 128) return;
        const int t = blk >> 10;
        const int b = blk & 1023;
        int it; __hip_bfloat16* x;
        if (t == 0) { it = 0; x = x0; }
        else if (t == 1) { it = targets[b] + 1; x = x1; }
        else { it = targets[B_SZ + b] + 36; x = x2; }
        float4 v = reinterpret_cast<const float4*>(emb + (size_t)it * DW_SZ)[tid];
        reinterpret_cast<ushort4*>(x + (size_t)b * XW)[tid] = cvt4(v);
    } else if (blk < 4096) {
        const int i = (blk - 3072) * 256 + tid;
        const float4 v = reinterpret_cast<const float4*>(enc_h)[i];
        reinterpret_cast<float4*>(h)[i] = v;
        reinterpret_cast<ushort4*>(h_bf)[i] = cvt4(v);
    } else {
        float* bt = (blk == 4096) ? bias0 : bias1;
        const float* ob = (blk == 4096) ? o0b : o1b;
        for (int j = tid; j < NGL; j += 256) {
            float v;
            if (j < H_SZ) v = b1[j];
            else if (j < 4 * H_SZ) v = b_hh[j - H_SZ];
            else if (j < 4 * H_SZ + V_SZ) v = ob[j - 4 * H_SZ];
            else v = 0.0f;
            bt[j] = v;
        }
    }
}

// ---------------- fused: blocks [0,nattn) = attention; rest = log-softmax ----------------
__global__ __launch_bounds__(256) void attn_ls_kernel(
    const __hip_bfloat16* __restrict__ enc,
    const __hip_bfloat16* __restrict__ enc_proj,
    const __hip_bfloat16* __restrict__ hgl,    // [B][NGL]; hproj at +0, logits at +4096
    const float* __restrict__ w2,
    __hip_bfloat16* __restrict__ x,
    float* __restrict__ outp,
    int nattn) {
    const int blk = blockIdx.x;
    const int tid = threadIdx.x;
    const int lane = tid & 63, wave = tid >> 6;
    __shared__ float s_e[S_SZ];
    __shared__ float s_red[4];
    __shared__ float s_bc;

    if (blk < nattn) {
        const int b = blk;
        float hp[16], wv[16];
        const unsigned short* hgrow = reinterpret_cast<const unsigned short*>(hgl) + (size_t)b * NGL;
#pragma unroll
        for (int p = 0; p < 4; ++p) {
            const int base = p * 256 + lane * 4;
            ushort4 hu = *reinterpret_cast<const ushort4*>(hgrow + base);
            float4 wq = *reinterpret_cast<const float4*>(w2 + base);
            hp[p * 4 + 0] = bfraw2f(hu.x); hp[p * 4 + 1] = bfraw2f(hu.y);
            hp[p * 4 + 2] = bfraw2f(hu.z); hp[p * 4 + 3] = bfraw2f(hu.w);
            wv[p * 4 + 0] = wq.x; wv[p * 4 + 1] = wq.y;
            wv[p * 4 + 2] = wq.z; wv[p * 4 + 3] = wq.w;
        }

        const unsigned short* ep0 = reinterpret_cast<const unsigned short*>(enc_proj) + (size_t)b * S_SZ * H_SZ;
#pragma unroll 2
        for (int i = 0; i < 10; ++i) {
            const int s = wave + 4 * i;
            const unsigned short* row = ep0 + (size_t)s * H_SZ;
            float acc = 0.f;
#pragma unroll
            for (int p = 0; p < 4; ++p) {
                ushort4 eu = *reinterpret_cast<const ushort4*>(row + p * 256 + lane * 4);
                acc += fast_tanh(bfraw2f(eu.x) + hp[p * 4 + 0]) * wv[p * 4 + 0]
                     + fast_tanh(bfraw2f(eu.y) + hp[p * 4 + 1]) * wv[p * 4 + 1]
                     + fast_tanh(bfraw2f(eu.z) + hp[p * 4 + 2]) * wv[p * 4 + 2]
                     + fast_tanh(bfraw2f(eu.w) + hp[p * 4 + 3]) * wv[p * 4 + 3];
            }
#pragma unroll
            for (int off = 32; off > 0; off >>= 1) acc += __shfl_down(acc, off);
            if (lane == 0) s_e[s] = acc;
        }
        __syncthreads();

        float m = -1e30f;
        for (int s = 0; s < S_SZ; ++s) m = fmaxf(m, s_e[s]);
        float sum = 0.f;
        for (int s = 0; s < S_SZ; ++s) sum += __expf(s_e[s] - m);
        const float inv = 1.0f / sum;

        const ushort4* enc_b = reinterpret_cast<const ushort4*>(enc + (size_t)b * S_SZ * H_SZ);
        float4 acc = make_float4(0.f, 0.f, 0.f, 0.f);
        for (int s = 0; s < S_SZ; ++s) {
            const float a = __expf(s_e[s] - m) * inv;
            ushort4 ev = enc_b[s * 256 + tid];
            acc.x += a * bfraw2f(ev.x); acc.y += a * bfraw2f(ev.y);
            acc.z += a * bfraw2f(ev.z); acc.w += a * bfraw2f(ev.w);
        }
        reinterpret_cast<ushort4*>(x + (size_t)b * XW + DW_SZ)[tid] = cvt4(acc);
    } else {
        const int b = blk - nattn;
        const ushort4* row4 = reinterpret_cast<const ushort4*>(
            reinterpret_cast<const unsigned short*>(hgl) + (size_t)b * NGL + 4096);
        float* orow = outp + (size_t)b * V_SZ;

        float m = -1e30f;
        for (int k = tid; k < V_SZ / 4; k += 256) {
            ushort4 u = row4[k];
            m = fmaxf(m, fmaxf(fmaxf(bfraw2f(u.x), bfraw2f(u.y)), fmaxf(bfraw2f(u.z), bfraw2f(u.w))));
        }
#pragma unroll
        for (int off = 32; off > 0; off >>= 1) m = fmaxf(m, __shfl_down(m, off));
        if (lane == 0) s_red[wave] = m;
        __syncthreads();
        if (tid == 0) s_bc = fmaxf(fmaxf(s_red[0], s_red[1]), fmaxf(s_red[2], s_red[3]));
        __syncthreads();
        m = s_bc;

        float sum = 0.f;
        for (int k = tid; k < V_SZ / 4; k += 256) {
            ushort4 u = row4[k];
            sum += expf(bfraw2f(u.x) - m) + expf(bfraw2f(u.y) - m)
                 + expf(bfraw2f(u.z) - m) + expf(bfraw2f(u.w) - m);
        }
#pragma unroll
        for (int off = 32; off > 0; off >>= 1) sum += __shfl_down(sum, off);
        __syncthreads();
        if (lane == 0) s_red[wave] = sum;
        __syncthreads();
        if (tid == 0) s_bc = logf(s_red[0] + s_red[1] + s_red[2] + s_red[3]) + m;
        __syncthreads();
        const float ls = s_bc;

        for (int k = tid; k < V_SZ / 4; k += 256) {
            ushort4 u = row4[k];
            float4 o = make_float4(bfraw2f(u.x) - ls, bfraw2f(u.y) - ls,
                                   bfraw2f(u.z) - ls, bfraw2f(u.w) - ls);
            reinterpret_cast<float4*>(orow)[k] = o;
        }
    }
}

// ---------------- GRU gate combine ----------------
__global__ __launch_bounds__(256) void gru_gate_kernel(
    const __hip_bfloat16* __restrict__ gi,
    const __hip_bfloat16* __restrict__ hgl,   // gh at +H, row stride NGL
    float* __restrict__ h,
    __hip_bfloat16* __restrict__ h_bf) {
    const int idx = blockIdx.x * 256 + threadIdx.x;
    const int b = idx >> 10;
    const int j = idx & 1023;
    const unsigned short* gib = reinterpret_cast<const unsigned short*>(gi) + (size_t)b * 3 * H_SZ;
    const unsigned short* ghb = reinterpret_cast<const unsigned short*>(hgl) + (size_t)b * NGL + H_SZ;
    const float i_r = bfraw2f(gib[j]), i_z = bfraw2f(gib[H_SZ + j]), i_n = bfraw2f(gib[2 * H_SZ + j]);
    const float h_r = bfraw2f(ghb[j]), h_z = bfraw2f(ghb[H_SZ + j]), h_n = bfraw2f(ghb[2 * H_SZ + j]);
    const float r = fast_sigmoid(i_r + h_r);
    const float z = fast_sigmoid(i_z + h_z);
    const float n = fast_tanh(i_n + r * h_n);
    const float hv = (1.0f - z) * n + z * h[idx];
    h[idx] = hv;
    h_bf[idx] = __float2bfloat16(hv);
}

extern "C" void kernel_launch(void* const* d_in, const int* in_sizes, int n_in,
                              void* d_out, int out_size, void* d_ws, size_t ws_size,
                              hipStream_t stream) {
    const float* enc    = (const float*)d_in[0];
    const float* enc_h  = (const float*)d_in[1];
    const int*   tgt    = (const int*)d_in[2];
    const float* emb    = (const float*)d_in[3];
    const float* w1     = (const float*)d_in[4];
    const float* b1     = (const float*)d_in[5];
    const float* w2     = (const float*)d_in[6];
    const float* w_ih   = (const float*)d_in[7];
    const float* w_hh   = (const float*)d_in[8];
    const float* b_ih   = (const float*)d_in[9];
    const float* b_hh   = (const float*)d_in[10];
    const float* out0_w = (const float*)d_in[11];
    const float* out0_b = (const float*)d_in[12];
    const float* out1_w = (const float*)d_in[13];
    const float* out1_b = (const float*)d_in[14];
    float* out = (float*)d_out;

    char* wp = (char*)d_ws;
    auto carve = [&](size_t bytes) { char* p = wp; wp += (bytes + 255) & ~(size_t)255; return p; };
    __hip_bfloat16* enc_bf  = (__hip_bfloat16*)carve((size_t)B_SZ * S_SZ * H_SZ * 2);
    __hip_bfloat16* encp_bf = (__hip_bfloat16*)carve((size_t)B_SZ * S_SZ * H_SZ * 2);
    __hip_bfloat16* w1a_bf  = (__hip_bfloat16*)carve((size_t)H_SZ * H_SZ * 2);
    __hip_bfloat16* wall0   = (__hip_bfloat16*)carve((size_t)NGL * H_SZ * 2);   // [w1h; whh; o0; pad]
    __hip_bfloat16* wall1   = (__hip_bfloat16*)carve((size_t)NGL * H_SZ * 2);   // [w1h; whh; o1; pad]
    __hip_bfloat16* wih_bf  = (__hip_bfloat16*)carve((size_t)3 * H_SZ * XW * 2);
    float*          bias0   = (float*)carve((size_t)NGL * 4);
    float*          bias1   = (float*)carve((size_t)NGL * 4);
    float*          h       = (float*)carve((size_t)B_SZ * H_SZ * 4);
    __hip_bfloat16* h_bf    = (__hip_bfloat16*)carve((size_t)B_SZ * H_SZ * 2);
    __hip_bfloat16* hgl     = (__hip_bfloat16*)carve((size_t)B_SZ * NGL * 2);   // [hproj|gh|logits|pad]
    __hip_bfloat16* x_bf[3];
    for (int t = 0; t < 3; ++t) x_bf[t] = (__hip_bfloat16*)carve((size_t)B_SZ * XW * 2);
    __hip_bfloat16* gi_bf   = (__hip_bfloat16*)carve((size_t)B_SZ * 3 * H_SZ * 2);

    // optional gie buffer (emb-part of gi, precomputed for all 3 steps); fallback if ws too small
    const size_t gie_bytes = (size_t)3 * B_SZ * 3 * H_SZ * 2;   // 18.9 MB
    __hip_bfloat16* gie = nullptr;
    if ((size_t)(wp - (char*)d_ws) + gie_bytes + 256 <= ws_size)
        gie = (__hip_bfloat16*)carve(gie_bytes);

    // --- prep ---
    cast_fast_kernel<<<CE6 / 1024, 256, 0, stream>>>(enc, w1, w_hh, w_ih, out0_w, out1_w,
                                                     enc_bf, w1a_bf, wall0, wall1, wih_bf);
    hipMemsetAsync(wall0 + (size_t)(4 * H_SZ + V_SZ) * H_SZ, 0, (size_t)96 * H_SZ * 2, stream);
    hipMemsetAsync(wall1 + (size_t)(4 * H_SZ + V_SZ) * H_SZ, 0, (size_t)96 * H_SZ * 2, stream);
    small_prep_kernel<<<4098, 256, 0, stream>>>(emb, tgt, x_bf[0], x_bf[1], x_bf[2],
                                                enc_h, h, h_bf, b1, b_hh, out0_b, out1_b,
                                                bias0, bias1);

    // gie = emb-part of gi for all 3 steps: x_bf[0..2] are contiguous -> M = 3B, K = 512
    if (gie) {
        gemm_bt_mfma<1, 0><<<(3 * B_SZ / 128) * 24, 256, 0, stream>>>(
            x_bf[0], XW, wih_bf, XW, nullptr, nullptr, 0, gie, 3 * H_SZ, 24, 3 * H_SZ, DW_SZ);
    }

    // enc_proj = enc @ w1[:, :H].T -- 128x256 counted-vmcnt pipeline (proven 103us)
    gemm_bt_pipe128<<<(B_SZ * S_SZ / 128) * (H_SZ / 256), 256, 3 * 24576, stream>>>(
        enc_bf, H_SZ, w1a_bf, H_SZ, encp_bf, H_SZ, H_SZ / 256, H_SZ);

    // hg(0): first 4096 cols of hgl = h0 @ wcat.T + [b1|b_hh]
    gemm_bt_mfma<1, 0><<<(B_SZ / 128) * 32, 256, 0, stream>>>(
        h_bf, H_SZ, wall0, H_SZ, bias0, nullptr, 0, hgl, NGL, 32, 4 * H_SZ, H_SZ);

    // attn(0) standalone
    attn_ls_kernel<<<B_SZ, 256, 0, stream>>>(enc_bf, encp_bf, hgl, w2, x_bf[0], out, B_SZ);

    for (int t = 0; t < 3; ++t) {
        // gi = x @ w_ih.T + b_ih  (bf16 out)
        if (gie) {
            // ctx-part only (K=1024) + precomputed emb-part via Cin
            gemm_bt_mfma<1, 0><<<(B_SZ / 128) * 24, 256, 0, stream>>>(
                x_bf[t] + DW_SZ, XW, wih_bf + DW_SZ, XW, b_ih,
                gie + (size_t)t * B_SZ * 3 * H_SZ, 3 * H_SZ,
                gi_bf, 3 * H_SZ, 24, 3 * H_SZ, H_SZ);
        } else {
            gemm_bt_mfma<1, 0><<<(B_SZ / 128) * 24, 256, 0, stream>>>(
                x_bf[t], XW, wih_bf, XW, b_ih, nullptr, 0, gi_bf, 3 * H_SZ, 24, 3 * H_SZ, XW);
        }

        gru_gate_kernel<<<(B_SZ * H_SZ) / 256, 256, 0, stream>>>(gi_bf, hgl, h, h_bf);

        // hgl = h @ wall_t.T + bias_t : [hg(t+1) | logits(t)]
        // logits weights: t==0 -> o0 (wall0), t==1 -> o1 (wall1), t==2 -> o0 (wall0)
        if (t == 0) {
            gemm_bt_mfma<1, 0><<<(B_SZ / 128) * 64, 256, 0, stream>>>(
                h_bf, H_SZ, wall0, H_SZ, bias0, nullptr, 0, hgl, NGL, 64, NGL, H_SZ);
        } else if (t == 1) {
            gemm_bt_mfma<1, 0><<<(B_SZ / 128) * 64, 256, 0, stream>>>(
                h_bf, H_SZ, wall1, H_SZ, bias1, nullptr, 0, hgl, NGL, 64, NGL, H_SZ);
        } else {
            gemm_bt_mfma<1, 0><<<(B_SZ / 128) * 32, 256, 0, stream>>>(
                h_bf, H_SZ, wall0 + (size_t)4 * H_SZ * H_SZ, H_SZ, bias0 + 4 * H_SZ, nullptr, 0,
                hgl + 4 * H_SZ, NGL, 32, 4 * H_SZ, H_SZ);
        }

        // fused: log-softmax(t) [+ attention(t+1) when t<2]
        float* outp = out + (size_t)t * B_SZ * V_SZ;
        if (t < 2) {
            attn_ls_kernel<<<2 * B_SZ, 256, 0, stream>>>(enc_bf, encp_bf, hgl, w2, x_bf[t + 1],
                                                         outp, B_SZ);
        } else {
            attn_ls_kernel<<<B_SZ, 256, 0, stream>>>(enc_bf, encp_bf, hgl, w2, x_bf[0],
                                                     outp, 0);
        }
    }
}

// Round 12
// 540.248 us; speedup vs baseline: 1.0811x; 1.0811x over previous
//
#include <hip/hip_runtime.h>
#include <hip/hip_bf16.h>
#include <math.h>

#define B_SZ 1024
#define S_SZ 40
#define H_SZ 1024
#define DW_SZ 512
#define V_SZ 4000
#define XW (DW_SZ + H_SZ)      // 1536
#define NGL 8192               // hgl row: [hproj(1024) | gh(3072) | logits(4000) | pad(96)]

typedef __bf16 bf16x8 __attribute__((ext_vector_type(8)));
typedef float f32x4 __attribute__((ext_vector_type(4)));

__device__ __forceinline__ float fast_tanh(float x) {
    return 1.0f - 2.0f / (1.0f + __expf(2.0f * x));
}
__device__ __forceinline__ float fast_sigmoid(float x) {
    return 1.0f / (1.0f + __expf(-x));
}
__device__ __forceinline__ float bfraw2f(unsigned short u) {
    return __uint_as_float(((unsigned)u) << 16);
}
__device__ __forceinline__ ushort4 cvt4(float4 v) {
    union { ushort4 u; __hip_bfloat16 h[4]; } o;
    o.h[0] = __float2bfloat16(v.x); o.h[1] = __float2bfloat16(v.y);
    o.h[2] = __float2bfloat16(v.z); o.h[3] = __float2bfloat16(v.w);
    return o.u;
}

#define GLL16(gp, lp)                                                                \
    __builtin_amdgcn_global_load_lds((const __attribute__((address_space(1))) void*)(gp), \
                                     (__attribute__((address_space(3))) void*)(lp), 16, 0, 0)

// ========== 128x256 tile, BK=32, 3-slot counted-vmcnt pipelined GEMM, 2 blocks/CU ==========
// (proven: 103 us, MfmaUtil ~35%, 0 bank conflicts)
__global__ __launch_bounds__(256, 2) void gemm_bt_pipe128(
    const __hip_bfloat16* __restrict__ A, int lda,
    const __hip_bfloat16* __restrict__ W, int ldw,
    __hip_bfloat16* __restrict__ C, int ldc,
    int nbx, int K) {
    extern __shared__ char smem[];   // 3 * 24576 bytes
    const int tid = threadIdx.x;
    const int lane = tid & 63;
    const int wave = tid >> 6;
    const int wm = wave >> 1, wn = wave & 1;
    const int fr = lane & 15, fq = lane >> 4;

    int bid = blockIdx.x;
    { const int cpx = gridDim.x >> 3; bid = (bid & 7) * cpx + (bid >> 3); }  // XCD swizzle
    const int by = bid / nbx;
    const int bm = by * 128;
    const int bn = (bid - by * nbx) * 256;

    const int r0 = tid >> 2;
    const int s0 = (tid & 3) ^ ((tid >> 3) & 3);
    const __hip_bfloat16* gA0 = A + (size_t)(bm + r0) * lda + s0 * 8;
    const __hip_bfloat16* gA1 = A + (size_t)(bm + r0 + 64) * lda + s0 * 8;
    const __hip_bfloat16* gW0 = W + (size_t)(bn + r0) * ldw + s0 * 8;
    const __hip_bfloat16* gW1 = W + (size_t)(bn + r0 + 64) * ldw + s0 * 8;
    const __hip_bfloat16* gW2 = W + (size_t)(bn + r0 + 128) * ldw + s0 * 8;
    const __hip_bfloat16* gW3 = W + (size_t)(bn + r0 + 192) * ldw + s0 * 8;
    const int dst0 = tid * 16;

    int aoff[4], boff[8];
#pragma unroll
    for (int mi = 0; mi < 4; ++mi) {
        const int row = wm * 64 + mi * 16 + fr;
        aoff[mi] = row * 64 + ((fq ^ ((row >> 1) & 3)) << 4);
    }
#pragma unroll
    for (int ni = 0; ni < 8; ++ni) {
        const int col = wn * 128 + ni * 16 + fr;
        boff[ni] = 8192 + col * 64 + ((fq ^ ((col >> 1) & 3)) << 4);
    }

    const int NT = K >> 5;
    f32x4 acc[4][8] = {};

#define STAGE_T(t)                                                    \
    do {                                                              \
        char* sb = smem + ((t) % 3) * 24576;                          \
        const int kk = (t) << 5;                                      \
        GLL16(gA0 + kk, sb + dst0);                                   \
        GLL16(gA1 + kk, sb + dst0 + 4096);                            \
        GLL16(gW0 + kk, sb + 8192 + dst0);                            \
        GLL16(gW1 + kk, sb + 8192 + dst0 + 4096);                     \
        GLL16(gW2 + kk, sb + 8192 + dst0 + 8192);                     \
        GLL16(gW3 + kk, sb + 8192 + dst0 + 12288);                    \
    } while (0)

    STAGE_T(0);
    STAGE_T(1);
    __builtin_amdgcn_sched_barrier(0);
    asm volatile("s_waitcnt vmcnt(6)" ::: "memory");
    __builtin_amdgcn_s_barrier();
    __builtin_amdgcn_sched_barrier(0);

    for (int t = 0; t < NT; ++t) {
        const char* sb = smem + (t % 3) * 24576;
        bf16x8 af[4], bg[8];
#pragma unroll
        for (int ni = 0; ni < 8; ++ni) bg[ni] = *reinterpret_cast<const bf16x8*>(sb + boff[ni]);
#pragma unroll
        for (int mi = 0; mi < 4; ++mi) af[mi] = *reinterpret_cast<const bf16x8*>(sb + aoff[mi]);

        if (t + 2 < NT) STAGE_T(t + 2);

        __builtin_amdgcn_s_setprio(1);
#pragma unroll
        for (int mi = 0; mi < 4; ++mi)
#pragma unroll
            for (int ni = 0; ni < 8; ++ni)
                acc[mi][ni] = __builtin_amdgcn_mfma_f32_16x16x32_bf16(af[mi], bg[ni], acc[mi][ni], 0, 0, 0);
        __builtin_amdgcn_s_setprio(0);

        if (t != NT - 1) {
            __builtin_amdgcn_sched_barrier(0);
            if (t + 2 < NT) asm volatile("s_waitcnt vmcnt(6)" ::: "memory");
            else            asm volatile("s_waitcnt vmcnt(0)" ::: "memory");
            __builtin_amdgcn_s_barrier();
            __builtin_amdgcn_sched_barrier(0);
        }
    }
#undef STAGE_T

#pragma unroll
    for (int mi = 0; mi < 4; ++mi) {
        const int row0 = bm + wm * 64 + mi * 16 + fq * 4;
#pragma unroll
        for (int ni = 0; ni < 8; ++ni) {
            const int col = bn + wn * 128 + ni * 16 + fr;
#pragma unroll
            for (int r = 0; r < 4; ++r)
                C[(size_t)(row0 + r) * ldc + col] = __float2bfloat16(acc[mi][ni][r]);
        }
    }
}

// ---------------- bf16 MFMA GEMM (128x128, 2-barrier): C = A@W.T + bias ----------------
template <int OB, int SWZ>
__global__ __launch_bounds__(256) void gemm_bt_mfma(
    const __hip_bfloat16* __restrict__ A, int lda,
    const __hip_bfloat16* __restrict__ W, int ldw,
    const float* __restrict__ bias,
    void* __restrict__ Cv, int ldc,
    int nbx, int N, int K) {
    __shared__ __align__(16) __hip_bfloat16 As[128 * 32];
    __shared__ __align__(16) __hip_bfloat16 Ws[128 * 32];
    const int tid = threadIdx.x;
    const int lane = tid & 63;
    const int wave = tid >> 6;

    int bid = blockIdx.x;
    if (SWZ) {
        const int cpx = gridDim.x >> 3;
        bid = (bid & 7) * cpx + (bid >> 3);
    }
    const int by = bid / nbx;
    const int bx = bid - by * nbx;
    const int bm = by * 128;
    const int bn = bx * 128;

    const int r0 = tid >> 2;
    const int kk = (tid & 3) * 8;
    const __hip_bfloat16* gA0 = A + (size_t)(bm + r0) * lda + kk;
    const __hip_bfloat16* gA1 = gA0 + (size_t)64 * lda;
    int wrow0 = bn + r0;      if (wrow0 > N - 1) wrow0 = N - 1;
    int wrow1 = bn + r0 + 64; if (wrow1 > N - 1) wrow1 = N - 1;
    const __hip_bfloat16* gW0 = W + (size_t)wrow0 * ldw + kk;
    const __hip_bfloat16* gW1 = W + (size_t)wrow1 * ldw + kk;
    char* As_c = (char*)As + tid * 16;
    char* Ws_c = (char*)Ws + tid * 16;

    const int wr = wave >> 1, wc = wave & 1;
    const int fr = lane & 15, fq = lane >> 4;
    const __hip_bfloat16* Ard = &As[(wr * 64 + fr) * 32 + fq * 8];
    const __hip_bfloat16* Wrd = &Ws[(wc * 64 + fr) * 32 + fq * 8];

    f32x4 acc[4][4] = {};

    for (int k0 = 0; k0 < K; k0 += 32) {
        __syncthreads();
        GLL16(gA0 + k0, As_c);
        GLL16(gA1 + k0, As_c + 4096);
        GLL16(gW0 + k0, Ws_c);
        GLL16(gW1 + k0, Ws_c + 4096);
        __syncthreads();

        bf16x8 af[4], bg[4];
#pragma unroll
        for (int i = 0; i < 4; ++i) {
            af[i] = *reinterpret_cast<const bf16x8*>(Ard + i * 16 * 32);
            bg[i] = *reinterpret_cast<const bf16x8*>(Wrd + i * 16 * 32);
        }
#pragma unroll
        for (int mi = 0; mi < 4; ++mi)
#pragma unroll
            for (int ni = 0; ni < 4; ++ni)
                acc[mi][ni] = __builtin_amdgcn_mfma_f32_16x16x32_bf16(af[mi], bg[ni], acc[mi][ni], 0, 0, 0);
    }

#pragma unroll
    for (int ni = 0; ni < 4; ++ni) {
        const int col = bn + wc * 64 + ni * 16 + fr;
        if (col >= N) continue;
        const float bb = bias ? bias[col] : 0.0f;
#pragma unroll
        for (int mi = 0; mi < 4; ++mi) {
            const int row0 = bm + wr * 64 + mi * 16 + fq * 4;
#pragma unroll
            for (int r = 0; r < 4; ++r) {
                const float v = acc[mi][ni][r] + bb;
                if (OB)
                    reinterpret_cast<__hip_bfloat16*>(Cv)[(size_t)(row0 + r) * ldc + col] = __float2bfloat16(v);
                else
                    reinterpret_cast<float*>(Cv)[(size_t)(row0 + r) * ldc + col] = v;
            }
        }
    }
}

// ---------------- fast cast v2: block-uniform segment, straight-line 4-load/4-store ----------------
// All segment sizes are multiples of 1024 float4 -> every 1024-f4 block lies in ONE segment.
// Block segment bases (in 1024-f4 blocks):
#define SB0 0                    // enc        (10240 blocks, flat)
#define SB1 10240                // w1a        (256, strided from w1 cols [0,256))
#define SB2 10496                // w1h dual   (256, strided from w1 cols [256,512) -> wall0+wall1)
#define SB3 10752                // whh dual   (768, flat -> wall0+wall1 @ +262144 u4)
#define SB4 11520                // wih        (1152, flat)
#define SB5 12672                // o0         (1000, flat -> wall0 @ +1048576 u4)
#define SB6 13672                // o1         (1000, flat -> wall1 @ +1048576 u4)
#define SB7 14672                // wall0 pad zero (24 blocks @ u4 2072576)
#define SB8 14696                // wall1 pad zero (24)
#define SBTOT 14720
__global__ __launch_bounds__(256) void cast_fast_kernel(
    const float* __restrict__ enc, const float* __restrict__ w1,
    const float* __restrict__ whh, const float* __restrict__ wih,
    const float* __restrict__ o0, const float* __restrict__ o1,
    __hip_bfloat16* __restrict__ enc_bf, __hip_bfloat16* __restrict__ w1a_bf,
    __hip_bfloat16* __restrict__ wall0, __hip_bfloat16* __restrict__ wall1,
    __hip_bfloat16* __restrict__ wih_bf) {
    const int blk = blockIdx.x;
    const int tid = threadIdx.x;
    ushort4* w0u = reinterpret_cast<ushort4*>(wall0);
    ushort4* w1u = reinterpret_cast<ushort4*>(wall1);

    if (blk < SB1) {                      // enc (flat)
        const int li = blk * 1024 + tid;
        const float4* s = reinterpret_cast<const float4*>(enc);
        float4 v0 = s[li], v1 = s[li + 256], v2 = s[li + 512], v3 = s[li + 768];
        ushort4* d = reinterpret_cast<ushort4*>(enc_bf);
        d[li] = cvt4(v0); d[li + 256] = cvt4(v1); d[li + 512] = cvt4(v2); d[li + 768] = cvt4(v3);
    } else if (blk < SB2) {               // w1[:, :H] (strided)
        const int r0 = (blk - SB1) * 4;
        const float4* s = reinterpret_cast<const float4*>(w1);
        float4 v0 = s[(r0 + 0) * 512 + tid], v1 = s[(r0 + 1) * 512 + tid],
               v2 = s[(r0 + 2) * 512 + tid], v3 = s[(r0 + 3) * 512 + tid];
        ushort4* d = reinterpret_cast<ushort4*>(w1a_bf);
        const int li = r0 * 256 + tid;
        d[li] = cvt4(v0); d[li + 256] = cvt4(v1); d[li + 512] = cvt4(v2); d[li + 768] = cvt4(v3);
    } else if (blk < SB3) {               // w1[:, H:] (strided, dual write)
        const int r0 = (blk - SB2) * 4;
        const float4* s = reinterpret_cast<const float4*>(w1);
        ushort4 u0 = cvt4(s[(r0 + 0) * 512 + 256 + tid]), u1 = cvt4(s[(r0 + 1) * 512 + 256 + tid]),
                u2 = cvt4(s[(r0 + 2) * 512 + 256 + tid]), u3 = cvt4(s[(r0 + 3) * 512 + 256 + tid]);
        const int li = r0 * 256 + tid;
        w0u[li] = u0; w0u[li + 256] = u1; w0u[li + 512] = u2; w0u[li + 768] = u3;
        w1u[li] = u0; w1u[li + 256] = u1; w1u[li + 512] = u2; w1u[li + 768] = u3;
    } else if (blk < SB4) {               // whh (flat, dual write)
        const int li = (blk - SB3) * 1024 + tid;
        const float4* s = reinterpret_cast<const float4*>(whh);
        ushort4 u0 = cvt4(s[li]), u1 = cvt4(s[li + 256]), u2 = cvt4(s[li + 512]), u3 = cvt4(s[li + 768]);
        w0u[262144 + li] = u0; w0u[262144 + li + 256] = u1;
        w0u[262144 + li + 512] = u2; w0u[262144 + li + 768] = u3;
        w1u[262144 + li] = u0; w1u[262144 + li + 256] = u1;
        w1u[262144 + li + 512] = u2; w1u[262144 + li + 768] = u3;
    } else if (blk < SB5) {               // wih (flat)
        const int li = (blk - SB4) * 1024 + tid;
        const float4* s = reinterpret_cast<const float4*>(wih);
        float4 v0 = s[li], v1 = s[li + 256], v2 = s[li + 512], v3 = s[li + 768];
        ushort4* d = reinterpret_cast<ushort4*>(wih_bf);
        d[li] = cvt4(v0); d[li + 256] = cvt4(v1); d[li + 512] = cvt4(v2); d[li + 768] = cvt4(v3);
    } else if (blk < SB6) {               // o0 (flat)
        const int li = (blk - SB5) * 1024 + tid;
        const float4* s = reinterpret_cast<const float4*>(o0);
        float4 v0 = s[li], v1 = s[li + 256], v2 = s[li + 512], v3 = s[li + 768];
        w0u[1048576 + li] = cvt4(v0); w0u[1048576 + li + 256] = cvt4(v1);
        w0u[1048576 + li + 512] = cvt4(v2); w0u[1048576 + li + 768] = cvt4(v3);
    } else if (blk < SB7) {               // o1 (flat)
        const int li = (blk - SB6) * 1024 + tid;
        const float4* s = reinterpret_cast<const float4*>(o1);
        float4 v0 = s[li], v1 = s[li + 256], v2 = s[li + 512], v3 = s[li + 768];
        w1u[1048576 + li] = cvt4(v0); w1u[1048576 + li + 256] = cvt4(v1);
        w1u[1048576 + li + 512] = cvt4(v2); w1u[1048576 + li + 768] = cvt4(v3);
    } else {                              // zero pad rows of wall0 / wall1
        const ushort4 z = make_ushort4(0, 0, 0, 0);
        if (blk < SB8) {
            const int li = 2072576 + (blk - SB7) * 1024 + tid;
            w0u[li] = z; w0u[li + 256] = z; w0u[li + 512] = z; w0u[li + 768] = z;
        } else {
            const int li = 2072576 + (blk - SB8) * 1024 + tid;
            w1u[li] = z; w1u[li + 256] = z; w1u[li + 512] = z; w1u[li + 768] = z;
        }
    }
}

// ---------------- small prep: emb prefill (<3072), h init (3072..4095), bias0/bias1 (4096/4097) ----------------
__global__ __launch_bounds__(256) void small_prep_kernel(
    const float* __restrict__ emb, const int* __restrict__ targets,
    __hip_bfloat16* __restrict__ x0, __hip_bfloat16* __restrict__ x1, __hip_bfloat16* __restrict__ x2,
    const float* __restrict__ enc_h, float* __restrict__ h, __hip_bfloat16* __restrict__ h_bf,
    const float* __restrict__ b1, const float* __restrict__ b_hh,
    const float* __restrict__ o0b, const float* __restrict__ o1b,
    float* __restrict__ bias0, float* __restrict__ bias1) {
    const int blk = blockIdx.x;
    const int tid = threadIdx.x;
    if (blk < 3072) {
        if (tid >= 128) return;
        const int t = blk >> 10;
        const int b = blk & 1023;
        int it; __hip_bfloat16* x;
        if (t == 0) { it = 0; x = x0; }
        else if (t == 1) { it = targets[b] + 1; x = x1; }
        else { it = targets[B_SZ + b] + 36; x = x2; }
        float4 v = reinterpret_cast<const float4*>(emb + (size_t)it * DW_SZ)[tid];
        reinterpret_cast<ushort4*>(x + (size_t)b * XW)[tid] = cvt4(v);
    } else if (blk < 4096) {
        const int i = (blk - 3072) * 256 + tid;
        const float4 v = reinterpret_cast<const float4*>(enc_h)[i];
        reinterpret_cast<float4*>(h)[i] = v;
        reinterpret_cast<ushort4*>(h_bf)[i] = cvt4(v);
    } else {
        float* bt = (blk == 4096) ? bias0 : bias1;
        const float* ob = (blk == 4096) ? o0b : o1b;
        for (int j = tid; j < NGL; j += 256) {
            float v;
            if (j < H_SZ) v = b1[j];
            else if (j < 4 * H_SZ) v = b_hh[j - H_SZ];
            else if (j < 4 * H_SZ + V_SZ) v = ob[j - 4 * H_SZ];
            else v = 0.0f;
            bt[j] = v;
        }
    }
}

// ---------------- fused: blocks [0,nattn) = attention; rest = log-softmax ----------------
__global__ __launch_bounds__(256) void attn_ls_kernel(
    const __hip_bfloat16* __restrict__ enc,
    const __hip_bfloat16* __restrict__ enc_proj,
    const __hip_bfloat16* __restrict__ hgl,    // [B][NGL]; hproj at +0, logits at +4096
    const float* __restrict__ w2,
    __hip_bfloat16* __restrict__ x,
    float* __restrict__ outp,
    int nattn) {
    const int blk = blockIdx.x;
    const int tid = threadIdx.x;
    const int lane = tid & 63, wave = tid >> 6;
    __shared__ float s_e[S_SZ];
    __shared__ float s_red[4];
    __shared__ float s_bc;

    if (blk < nattn) {
        const int b = blk;
        float hp[16], wv[16];
        const unsigned short* hgrow = reinterpret_cast<const unsigned short*>(hgl) + (size_t)b * NGL;
#pragma unroll
        for (int p = 0; p < 4; ++p) {
            const int base = p * 256 + lane * 4;
            ushort4 hu = *reinterpret_cast<const ushort4*>(hgrow + base);
            float4 wq = *reinterpret_cast<const float4*>(w2 + base);
            hp[p * 4 + 0] = bfraw2f(hu.x); hp[p * 4 + 1] = bfraw2f(hu.y);
            hp[p * 4 + 2] = bfraw2f(hu.z); hp[p * 4 + 3] = bfraw2f(hu.w);
            wv[p * 4 + 0] = wq.x; wv[p * 4 + 1] = wq.y;
            wv[p * 4 + 2] = wq.z; wv[p * 4 + 3] = wq.w;
        }

        const unsigned short* ep0 = reinterpret_cast<const unsigned short*>(enc_proj) + (size_t)b * S_SZ * H_SZ;
#pragma unroll 2
        for (int i = 0; i < 10; ++i) {
            const int s = wave + 4 * i;
            const unsigned short* row = ep0 + (size_t)s * H_SZ;
            float acc = 0.f;
#pragma unroll
            for (int p = 0; p < 4; ++p) {
                ushort4 eu = *reinterpret_cast<const ushort4*>(row + p * 256 + lane * 4);
                acc += fast_tanh(bfraw2f(eu.x) + hp[p * 4 + 0]) * wv[p * 4 + 0]
                     + fast_tanh(bfraw2f(eu.y) + hp[p * 4 + 1]) * wv[p * 4 + 1]
                     + fast_tanh(bfraw2f(eu.z) + hp[p * 4 + 2]) * wv[p * 4 + 2]
                     + fast_tanh(bfraw2f(eu.w) + hp[p * 4 + 3]) * wv[p * 4 + 3];
            }
#pragma unroll
            for (int off = 32; off > 0; off >>= 1) acc += __shfl_down(acc, off);
            if (lane == 0) s_e[s] = acc;
        }
        __syncthreads();

        float m = -1e30f;
        for (int s = 0; s < S_SZ; ++s) m = fmaxf(m, s_e[s]);
        float sum = 0.f;
        for (int s = 0; s < S_SZ; ++s) sum += __expf(s_e[s] - m);
        const float inv = 1.0f / sum;

        const ushort4* enc_b = reinterpret_cast<const ushort4*>(enc + (size_t)b * S_SZ * H_SZ);
        float4 acc = make_float4(0.f, 0.f, 0.f, 0.f);
        for (int s = 0; s < S_SZ; ++s) {
            const float a = __expf(s_e[s] - m) * inv;
            ushort4 ev = enc_b[s * 256 + tid];
            acc.x += a * bfraw2f(ev.x); acc.y += a * bfraw2f(ev.y);
            acc.z += a * bfraw2f(ev.z); acc.w += a * bfraw2f(ev.w);
        }
        reinterpret_cast<ushort4*>(x + (size_t)b * XW + DW_SZ)[tid] = cvt4(acc);
    } else {
        const int b = blk - nattn;
        const ushort4* row4 = reinterpret_cast<const ushort4*>(
            reinterpret_cast<const unsigned short*>(hgl) + (size_t)b * NGL + 4096);
        float* orow = outp + (size_t)b * V_SZ;

        float m = -1e30f;
        for (int k = tid; k < V_SZ / 4; k += 256) {
            ushort4 u = row4[k];
            m = fmaxf(m, fmaxf(fmaxf(bfraw2f(u.x), bfraw2f(u.y)), fmaxf(bfraw2f(u.z), bfraw2f(u.w))));
        }
#pragma unroll
        for (int off = 32; off > 0; off >>= 1) m = fmaxf(m, __shfl_down(m, off));
        if (lane == 0) s_red[wave] = m;
        __syncthreads();
        if (tid == 0) s_bc = fmaxf(fmaxf(s_red[0], s_red[1]), fmaxf(s_red[2], s_red[3]));
        __syncthreads();
        m = s_bc;

        float sum = 0.f;
        for (int k = tid; k < V_SZ / 4; k += 256) {
            ushort4 u = row4[k];
            sum += expf(bfraw2f(u.x) - m) + expf(bfraw2f(u.y) - m)
                 + expf(bfraw2f(u.z) - m) + expf(bfraw2f(u.w) - m);
        }
#pragma unroll
        for (int off = 32; off > 0; off >>= 1) sum += __shfl_down(sum, off);
        __syncthreads();
        if (lane == 0) s_red[wave] = sum;
        __syncthreads();
        if (tid == 0) s_bc = logf(s_red[0] + s_red[1] + s_red[2] + s_red[3]) + m;
        __syncthreads();
        const float ls = s_bc;

        for (int k = tid; k < V_SZ / 4; k += 256) {
            ushort4 u = row4[k];
            float4 o = make_float4(bfraw2f(u.x) - ls, bfraw2f(u.y) - ls,
                                   bfraw2f(u.z) - ls, bfraw2f(u.w) - ls);
            reinterpret_cast<float4*>(orow)[k] = o;
        }
    }
}

// ---------------- GRU gate combine ----------------
__global__ __launch_bounds__(256) void gru_gate_kernel(
    const __hip_bfloat16* __restrict__ gi,
    const __hip_bfloat16* __restrict__ hgl,   // gh at +H, row stride NGL
    float* __restrict__ h,
    __hip_bfloat16* __restrict__ h_bf) {
    const int idx = blockIdx.x * 256 + threadIdx.x;
    const int b = idx >> 10;
    const int j = idx & 1023;
    const unsigned short* gib = reinterpret_cast<const unsigned short*>(gi) + (size_t)b * 3 * H_SZ;
    const unsigned short* ghb = reinterpret_cast<const unsigned short*>(hgl) + (size_t)b * NGL + H_SZ;
    const float i_r = bfraw2f(gib[j]), i_z = bfraw2f(gib[H_SZ + j]), i_n = bfraw2f(gib[2 * H_SZ + j]);
    const float h_r = bfraw2f(ghb[j]), h_z = bfraw2f(ghb[H_SZ + j]), h_n = bfraw2f(ghb[2 * H_SZ + j]);
    const float r = fast_sigmoid(i_r + h_r);
    const float z = fast_sigmoid(i_z + h_z);
    const float n = fast_tanh(i_n + r * h_n);
    const float hv = (1.0f - z) * n + z * h[idx];
    h[idx] = hv;
    h_bf[idx] = __float2bfloat16(hv);
}

extern "C" void kernel_launch(void* const* d_in, const int* in_sizes, int n_in,
                              void* d_out, int out_size, void* d_ws, size_t ws_size,
                              hipStream_t stream) {
    const float* enc    = (const float*)d_in[0];
    const float* enc_h  = (const float*)d_in[1];
    const int*   tgt    = (const int*)d_in[2];
    const float* emb    = (const float*)d_in[3];
    const float* w1     = (const float*)d_in[4];
    const float* b1     = (const float*)d_in[5];
    const float* w2     = (const float*)d_in[6];
    const float* w_ih   = (const float*)d_in[7];
    const float* w_hh   = (const float*)d_in[8];
    const float* b_ih   = (const float*)d_in[9];
    const float* b_hh   = (const float*)d_in[10];
    const float* out0_w = (const float*)d_in[11];
    const float* out0_b = (const float*)d_in[12];
    const float* out1_w = (const float*)d_in[13];
    const float* out1_b = (const float*)d_in[14];
    float* out = (float*)d_out;

    char* wp = (char*)d_ws;
    auto carve = [&](size_t bytes) { char* p = wp; wp += (bytes + 255) & ~(size_t)255; return p; };
    __hip_bfloat16* enc_bf  = (__hip_bfloat16*)carve((size_t)B_SZ * S_SZ * H_SZ * 2);
    __hip_bfloat16* encp_bf = (__hip_bfloat16*)carve((size_t)B_SZ * S_SZ * H_SZ * 2);
    __hip_bfloat16* w1a_bf  = (__hip_bfloat16*)carve((size_t)H_SZ * H_SZ * 2);
    __hip_bfloat16* wall0   = (__hip_bfloat16*)carve((size_t)NGL * H_SZ * 2);   // [w1h; whh; o0; pad]
    __hip_bfloat16* wall1   = (__hip_bfloat16*)carve((size_t)NGL * H_SZ * 2);   // [w1h; whh; o1; pad]
    __hip_bfloat16* wih_bf  = (__hip_bfloat16*)carve((size_t)3 * H_SZ * XW * 2);
    float*          bias0   = (float*)carve((size_t)NGL * 4);
    float*          bias1   = (float*)carve((size_t)NGL * 4);
    float*          h       = (float*)carve((size_t)B_SZ * H_SZ * 4);
    __hip_bfloat16* h_bf    = (__hip_bfloat16*)carve((size_t)B_SZ * H_SZ * 2);
    __hip_bfloat16* hgl     = (__hip_bfloat16*)carve((size_t)B_SZ * NGL * 2);   // [hproj|gh|logits|pad]
    __hip_bfloat16* x_bf[3];
    for (int t = 0; t < 3; ++t) x_bf[t] = (__hip_bfloat16*)carve((size_t)B_SZ * XW * 2);
    __hip_bfloat16* gi_bf   = (__hip_bfloat16*)carve((size_t)B_SZ * 3 * H_SZ * 2);

    // --- prep: 2 launches (pad-zeroing folded into cast) ---
    cast_fast_kernel<<<SBTOT, 256, 0, stream>>>(enc, w1, w_hh, w_ih, out0_w, out1_w,
                                                enc_bf, w1a_bf, wall0, wall1, wih_bf);
    small_prep_kernel<<<4098, 256, 0, stream>>>(emb, tgt, x_bf[0], x_bf[1], x_bf[2],
                                                enc_h, h, h_bf, b1, b_hh, out0_b, out1_b,
                                                bias0, bias1);

    // enc_proj = enc @ w1[:, :H].T -- 128x256 counted-vmcnt pipeline (proven 103us)
    gemm_bt_pipe128<<<(B_SZ * S_SZ / 128) * (H_SZ / 256), 256, 3 * 24576, stream>>>(
        enc_bf, H_SZ, w1a_bf, H_SZ, encp_bf, H_SZ, H_SZ / 256, H_SZ);

    // hg(0): first 4096 cols of hgl = h0 @ wcat.T + [b1|b_hh]
    gemm_bt_mfma<1, 0><<<(B_SZ / 128) * 32, 256, 0, stream>>>(
        h_bf, H_SZ, wall0, H_SZ, bias0, hgl, NGL, 32, 4 * H_SZ, H_SZ);

    // attn(0) standalone
    attn_ls_kernel<<<B_SZ, 256, 0, stream>>>(enc_bf, encp_bf, hgl, w2, x_bf[0], out, B_SZ);

    for (int t = 0; t < 3; ++t) {
        // gi = x @ w_ih.T + b_ih  (bf16 out, K = 1536)
        gemm_bt_mfma<1, 0><<<(B_SZ / 128) * 24, 256, 0, stream>>>(
            x_bf[t], XW, wih_bf, XW, b_ih, gi_bf, 3 * H_SZ, 24, 3 * H_SZ, XW);

        gru_gate_kernel<<<(B_SZ * H_SZ) / 256, 256, 0, stream>>>(gi_bf, hgl, h, h_bf);

        // hgl = h @ wall_t.T + bias_t : [hg(t+1) | logits(t)]
        // logits weights: t==0 -> o0 (wall0), t==1 -> o1 (wall1), t==2 -> o0 (wall0)
        if (t == 0) {
            gemm_bt_mfma<1, 0><<<(B_SZ / 128) * 64, 256, 0, stream>>>(
                h_bf, H_SZ, wall0, H_SZ, bias0, hgl, NGL, 64, NGL, H_SZ);
        } else if (t == 1) {
            gemm_bt_mfma<1, 0><<<(B_SZ / 128) * 64, 256, 0, stream>>>(
                h_bf, H_SZ, wall1, H_SZ, bias1, hgl, NGL, 64, NGL, H_SZ);
        } else {
            gemm_bt_mfma<1, 0><<<(B_SZ / 128) * 32, 256, 0, stream>>>(
                h_bf, H_SZ, wall0 + (size_t)4 * H_SZ * H_SZ, H_SZ, bias0 + 4 * H_SZ,
                hgl + 4 * H_SZ, NGL, 32, 4 * H_SZ, H_SZ);
        }

        // fused: log-softmax(t) [+ attention(t+1) when t<2]
        float* outp = out + (size_t)t * B_SZ * V_SZ;
        if (t < 2) {
            attn_ls_kernel<<<2 * B_SZ, 256, 0, stream>>>(enc_bf, encp_bf, hgl, w2, x_bf[t + 1],
                                                         outp, B_SZ);
        } else {
            attn_ls_kernel<<<B_SZ, 256, 0, stream>>>(enc_bf, encp_bf, hgl, w2, x_bf[0],
                                                     outp, 0);
        }
    }
}

// Round 13
// 512.790 us; speedup vs baseline: 1.1390x; 1.0535x over previous
//
#include <hip/hip_runtime.h>
#include <hip/hip_bf16.h>
#include <math.h>

#define B_SZ 1024
#define S_SZ 40
#define H_SZ 1024
#define DW_SZ 512
#define V_SZ 4000
#define XW (DW_SZ + H_SZ)      // 1536
#define NGL 8192               // hgl row: [hproj(1024) | gh(3072) | logits(4000) | pad(96)]

typedef __bf16 bf16x8 __attribute__((ext_vector_type(8)));
typedef float f32x4 __attribute__((ext_vector_type(4)));

__device__ __forceinline__ float fast_tanh(float x) {
    return 1.0f - 2.0f / (1.0f + __expf(2.0f * x));
}
__device__ __forceinline__ float fast_sigmoid(float x) {
    return 1.0f / (1.0f + __expf(-x));
}
__device__ __forceinline__ float bfraw2f(unsigned short u) {
    return __uint_as_float(((unsigned)u) << 16);
}
__device__ __forceinline__ ushort4 cvt4(float4 v) {
    union { ushort4 u; __hip_bfloat16 h[4]; } o;
    o.h[0] = __float2bfloat16(v.x); o.h[1] = __float2bfloat16(v.y);
    o.h[2] = __float2bfloat16(v.z); o.h[3] = __float2bfloat16(v.w);
    return o.u;
}

#define GLL16(gp, lp)                                                                \
    __builtin_amdgcn_global_load_lds((const __attribute__((address_space(1))) void*)(gp), \
                                     (__attribute__((address_space(3))) void*)(lp), 16, 0, 0)

// ========== 128x256 tile, BK=32, 3-slot counted-vmcnt pipelined GEMM, 2 blocks/CU ==========
// (proven: 846 TF, MfmaUtil ~35%, 0 bank conflicts). Now with optional bias (epilogue-only).
// Requirements: M%128==0, N%256==0, K%32==0, K/32>=3, grid%8==0. bf16 out.
__global__ __launch_bounds__(256, 2) void gemm_bt_pipe128(
    const __hip_bfloat16* __restrict__ A, int lda,
    const __hip_bfloat16* __restrict__ W, int ldw,
    const float* __restrict__ bias,
    __hip_bfloat16* __restrict__ C, int ldc,
    int nbx, int K) {
    extern __shared__ char smem[];   // 3 * 24576 bytes
    const int tid = threadIdx.x;
    const int lane = tid & 63;
    const int wave = tid >> 6;
    const int wm = wave >> 1, wn = wave & 1;
    const int fr = lane & 15, fq = lane >> 4;

    int bid = blockIdx.x;
    { const int cpx = gridDim.x >> 3; bid = (bid & 7) * cpx + (bid >> 3); }  // XCD swizzle
    const int by = bid / nbx;
    const int bm = by * 128;
    const int bn = (bid - by * nbx) * 256;

    const int r0 = tid >> 2;
    const int s0 = (tid & 3) ^ ((tid >> 3) & 3);
    const __hip_bfloat16* gA0 = A + (size_t)(bm + r0) * lda + s0 * 8;
    const __hip_bfloat16* gA1 = A + (size_t)(bm + r0 + 64) * lda + s0 * 8;
    const __hip_bfloat16* gW0 = W + (size_t)(bn + r0) * ldw + s0 * 8;
    const __hip_bfloat16* gW1 = W + (size_t)(bn + r0 + 64) * ldw + s0 * 8;
    const __hip_bfloat16* gW2 = W + (size_t)(bn + r0 + 128) * ldw + s0 * 8;
    const __hip_bfloat16* gW3 = W + (size_t)(bn + r0 + 192) * ldw + s0 * 8;
    const int dst0 = tid * 16;

    int aoff[4], boff[8];
#pragma unroll
    for (int mi = 0; mi < 4; ++mi) {
        const int row = wm * 64 + mi * 16 + fr;
        aoff[mi] = row * 64 + ((fq ^ ((row >> 1) & 3)) << 4);
    }
#pragma unroll
    for (int ni = 0; ni < 8; ++ni) {
        const int col = wn * 128 + ni * 16 + fr;
        boff[ni] = 8192 + col * 64 + ((fq ^ ((col >> 1) & 3)) << 4);
    }

    const int NT = K >> 5;
    f32x4 acc[4][8] = {};

#define STAGE_T(t)                                                    \
    do {                                                              \
        char* sb = smem + ((t) % 3) * 24576;                          \
        const int kk = (t) << 5;                                      \
        GLL16(gA0 + kk, sb + dst0);                                   \
        GLL16(gA1 + kk, sb + dst0 + 4096);                            \
        GLL16(gW0 + kk, sb + 8192 + dst0);                            \
        GLL16(gW1 + kk, sb + 8192 + dst0 + 4096);                     \
        GLL16(gW2 + kk, sb + 8192 + dst0 + 8192);                     \
        GLL16(gW3 + kk, sb + 8192 + dst0 + 12288);                    \
    } while (0)

    STAGE_T(0);
    STAGE_T(1);
    __builtin_amdgcn_sched_barrier(0);
    asm volatile("s_waitcnt vmcnt(6)" ::: "memory");
    __builtin_amdgcn_s_barrier();
    __builtin_amdgcn_sched_barrier(0);

    for (int t = 0; t < NT; ++t) {
        const char* sb = smem + (t % 3) * 24576;
        bf16x8 af[4], bg[8];
#pragma unroll
        for (int ni = 0; ni < 8; ++ni) bg[ni] = *reinterpret_cast<const bf16x8*>(sb + boff[ni]);
#pragma unroll
        for (int mi = 0; mi < 4; ++mi) af[mi] = *reinterpret_cast<const bf16x8*>(sb + aoff[mi]);

        if (t + 2 < NT) STAGE_T(t + 2);

        __builtin_amdgcn_s_setprio(1);
#pragma unroll
        for (int mi = 0; mi < 4; ++mi)
#pragma unroll
            for (int ni = 0; ni < 8; ++ni)
                acc[mi][ni] = __builtin_amdgcn_mfma_f32_16x16x32_bf16(af[mi], bg[ni], acc[mi][ni], 0, 0, 0);
        __builtin_amdgcn_s_setprio(0);

        if (t != NT - 1) {
            __builtin_amdgcn_sched_barrier(0);
            if (t + 2 < NT) asm volatile("s_waitcnt vmcnt(6)" ::: "memory");
            else            asm volatile("s_waitcnt vmcnt(0)" ::: "memory");
            __builtin_amdgcn_s_barrier();
            __builtin_amdgcn_sched_barrier(0);
        }
    }
#undef STAGE_T

    // epilogue: C/D layout col=lane&15, row=(lane>>4)*4+reg
#pragma unroll
    for (int ni = 0; ni < 8; ++ni) {
        const int col = bn + wn * 128 + ni * 16 + fr;
        const float bb = bias ? bias[col] : 0.0f;
#pragma unroll
        for (int mi = 0; mi < 4; ++mi) {
            const int row0 = bm + wm * 64 + mi * 16 + fq * 4;
#pragma unroll
            for (int r = 0; r < 4; ++r)
                C[(size_t)(row0 + r) * ldc + col] = __float2bfloat16(acc[mi][ni][r] + bb);
        }
    }
}

// ---------------- fast cast v2: block-uniform segment, straight-line 4-load/4-store ----------------
#define SB0 0                    // enc        (10240 blocks, flat)
#define SB1 10240                // w1a        (256, strided from w1 cols [0,256))
#define SB2 10496                // w1h dual   (256, strided from w1 cols [256,512) -> wall0+wall1)
#define SB3 10752                // whh dual   (768, flat -> wall0+wall1 @ +262144 u4)
#define SB4 11520                // wih        (1152, flat)
#define SB5 12672                // o0         (1000, flat -> wall0 @ +1048576 u4)
#define SB6 13672                // o1         (1000, flat -> wall1 @ +1048576 u4)
#define SB7 14672                // wall0 pad zero (24 blocks @ u4 2072576)
#define SB8 14696                // wall1 pad zero (24)
#define SBTOT 14720
__global__ __launch_bounds__(256) void cast_fast_kernel(
    const float* __restrict__ enc, const float* __restrict__ w1,
    const float* __restrict__ whh, const float* __restrict__ wih,
    const float* __restrict__ o0, const float* __restrict__ o1,
    __hip_bfloat16* __restrict__ enc_bf, __hip_bfloat16* __restrict__ w1a_bf,
    __hip_bfloat16* __restrict__ wall0, __hip_bfloat16* __restrict__ wall1,
    __hip_bfloat16* __restrict__ wih_bf) {
    const int blk = blockIdx.x;
    const int tid = threadIdx.x;
    ushort4* w0u = reinterpret_cast<ushort4*>(wall0);
    ushort4* w1u = reinterpret_cast<ushort4*>(wall1);

    if (blk < SB1) {                      // enc (flat)
        const int li = blk * 1024 + tid;
        const float4* s = reinterpret_cast<const float4*>(enc);
        float4 v0 = s[li], v1 = s[li + 256], v2 = s[li + 512], v3 = s[li + 768];
        ushort4* d = reinterpret_cast<ushort4*>(enc_bf);
        d[li] = cvt4(v0); d[li + 256] = cvt4(v1); d[li + 512] = cvt4(v2); d[li + 768] = cvt4(v3);
    } else if (blk < SB2) {               // w1[:, :H] (strided)
        const int r0 = (blk - SB1) * 4;
        const float4* s = reinterpret_cast<const float4*>(w1);
        float4 v0 = s[(r0 + 0) * 512 + tid], v1 = s[(r0 + 1) * 512 + tid],
               v2 = s[(r0 + 2) * 512 + tid], v3 = s[(r0 + 3) * 512 + tid];
        ushort4* d = reinterpret_cast<ushort4*>(w1a_bf);
        const int li = r0 * 256 + tid;
        d[li] = cvt4(v0); d[li + 256] = cvt4(v1); d[li + 512] = cvt4(v2); d[li + 768] = cvt4(v3);
    } else if (blk < SB3) {               // w1[:, H:] (strided, dual write)
        const int r0 = (blk - SB2) * 4;
        const float4* s = reinterpret_cast<const float4*>(w1);
        ushort4 u0 = cvt4(s[(r0 + 0) * 512 + 256 + tid]), u1 = cvt4(s[(r0 + 1) * 512 + 256 + tid]),
                u2 = cvt4(s[(r0 + 2) * 512 + 256 + tid]), u3 = cvt4(s[(r0 + 3) * 512 + 256 + tid]);
        const int li = r0 * 256 + tid;
        w0u[li] = u0; w0u[li + 256] = u1; w0u[li + 512] = u2; w0u[li + 768] = u3;
        w1u[li] = u0; w1u[li + 256] = u1; w1u[li + 512] = u2; w1u[li + 768] = u3;
    } else if (blk < SB4) {               // whh (flat, dual write)
        const int li = (blk - SB3) * 1024 + tid;
        const float4* s = reinterpret_cast<const float4*>(whh);
        ushort4 u0 = cvt4(s[li]), u1 = cvt4(s[li + 256]), u2 = cvt4(s[li + 512]), u3 = cvt4(s[li + 768]);
        w0u[262144 + li] = u0; w0u[262144 + li + 256] = u1;
        w0u[262144 + li + 512] = u2; w0u[262144 + li + 768] = u3;
        w1u[262144 + li] = u0; w1u[262144 + li + 256] = u1;
        w1u[262144 + li + 512] = u2; w1u[262144 + li + 768] = u3;
    } else if (blk < SB5) {               // wih (flat)
        const int li = (blk - SB4) * 1024 + tid;
        const float4* s = reinterpret_cast<const float4*>(wih);
        float4 v0 = s[li], v1 = s[li + 256], v2 = s[li + 512], v3 = s[li + 768];
        ushort4* d = reinterpret_cast<ushort4*>(wih_bf);
        d[li] = cvt4(v0); d[li + 256] = cvt4(v1); d[li + 512] = cvt4(v2); d[li + 768] = cvt4(v3);
    } else if (blk < SB6) {               // o0 (flat)
        const int li = (blk - SB5) * 1024 + tid;
        const float4* s = reinterpret_cast<const float4*>(o0);
        float4 v0 = s[li], v1 = s[li + 256], v2 = s[li + 512], v3 = s[li + 768];
        w0u[1048576 + li] = cvt4(v0); w0u[1048576 + li + 256] = cvt4(v1);
        w0u[1048576 + li + 512] = cvt4(v2); w0u[1048576 + li + 768] = cvt4(v3);
    } else if (blk < SB7) {               // o1 (flat)
        const int li = (blk - SB6) * 1024 + tid;
        const float4* s = reinterpret_cast<const float4*>(o1);
        float4 v0 = s[li], v1 = s[li + 256], v2 = s[li + 512], v3 = s[li + 768];
        w1u[1048576 + li] = cvt4(v0); w1u[1048576 + li + 256] = cvt4(v1);
        w1u[1048576 + li + 512] = cvt4(v2); w1u[1048576 + li + 768] = cvt4(v3);
    } else {                              // zero pad rows of wall0 / wall1
        const ushort4 z = make_ushort4(0, 0, 0, 0);
        if (blk < SB8) {
            const int li = 2072576 + (blk - SB7) * 1024 + tid;
            w0u[li] = z; w0u[li + 256] = z; w0u[li + 512] = z; w0u[li + 768] = z;
        } else {
            const int li = 2072576 + (blk - SB8) * 1024 + tid;
            w1u[li] = z; w1u[li + 256] = z; w1u[li + 512] = z; w1u[li + 768] = z;
        }
    }
}

// ---------------- small prep: emb prefill (<3072), h init (3072..4095), bias0/bias1 (4096/4097) ----------------
__global__ __launch_bounds__(256) void small_prep_kernel(
    const float* __restrict__ emb, const int* __restrict__ targets,
    __hip_bfloat16* __restrict__ x0, __hip_bfloat16* __restrict__ x1, __hip_bfloat16* __restrict__ x2,
    const float* __restrict__ enc_h, float* __restrict__ h, __hip_bfloat16* __restrict__ h_bf,
    const float* __restrict__ b1, const float* __restrict__ b_hh,
    const float* __restrict__ o0b, const float* __restrict__ o1b,
    float* __restrict__ bias0, float* __restrict__ bias1) {
    const int blk = blockIdx.x;
    const int tid = threadIdx.x;
    if (blk < 3072) {
        if (tid >= 128) return;
        const int t = blk >> 10;
        const int b = blk & 1023;
        int it; __hip_bfloat16* x;
        if (t == 0) { it = 0; x = x0; }
        else if (t == 1) { it = targets[b] + 1; x = x1; }
        else { it = targets[B_SZ + b] + 36; x = x2; }
        float4 v = reinterpret_cast<const float4*>(emb + (size_t)it * DW_SZ)[tid];
        reinterpret_cast<ushort4*>(x + (size_t)b * XW)[tid] = cvt4(v);
    } else if (blk < 4096) {
        const int i = (blk - 3072) * 256 + tid;
        const float4 v = reinterpret_cast<const float4*>(enc_h)[i];
        reinterpret_cast<float4*>(h)[i] = v;
        reinterpret_cast<ushort4*>(h_bf)[i] = cvt4(v);
    } else {
        float* bt = (blk == 4096) ? bias0 : bias1;
        const float* ob = (blk == 4096) ? o0b : o1b;
        for (int j = tid; j < NGL; j += 256) {
            float v;
            if (j < H_SZ) v = b1[j];
            else if (j < 4 * H_SZ) v = b_hh[j - H_SZ];
            else if (j < 4 * H_SZ + V_SZ) v = ob[j - 4 * H_SZ];
            else v = 0.0f;
            bt[j] = v;
        }
    }
}

// ---------------- fused: blocks [0,nattn) = attention; rest = log-softmax ----------------
__global__ __launch_bounds__(256) void attn_ls_kernel(
    const __hip_bfloat16* __restrict__ enc,
    const __hip_bfloat16* __restrict__ enc_proj,
    const __hip_bfloat16* __restrict__ hgl,    // [B][NGL]; hproj at +0, logits at +4096
    const float* __restrict__ w2,
    __hip_bfloat16* __restrict__ x,
    float* __restrict__ outp,
    int nattn) {
    const int blk = blockIdx.x;
    const int tid = threadIdx.x;
    const int lane = tid & 63, wave = tid >> 6;
    __shared__ float s_e[S_SZ];
    __shared__ float s_red[4];
    __shared__ float s_bc;

    if (blk < nattn) {
        const int b = blk;
        float hp[16], wv[16];
        const unsigned short* hgrow = reinterpret_cast<const unsigned short*>(hgl) + (size_t)b * NGL;
#pragma unroll
        for (int p = 0; p < 4; ++p) {
            const int base = p * 256 + lane * 4;
            ushort4 hu = *reinterpret_cast<const ushort4*>(hgrow + base);
            float4 wq = *reinterpret_cast<const float4*>(w2 + base);
            hp[p * 4 + 0] = bfraw2f(hu.x); hp[p * 4 + 1] = bfraw2f(hu.y);
            hp[p * 4 + 2] = bfraw2f(hu.z); hp[p * 4 + 3] = bfraw2f(hu.w);
            wv[p * 4 + 0] = wq.x; wv[p * 4 + 1] = wq.y;
            wv[p * 4 + 2] = wq.z; wv[p * 4 + 3] = wq.w;
        }

        const unsigned short* ep0 = reinterpret_cast<const unsigned short*>(enc_proj) + (size_t)b * S_SZ * H_SZ;
#pragma unroll 2
        for (int i = 0; i < 10; ++i) {
            const int s = wave + 4 * i;
            const unsigned short* row = ep0 + (size_t)s * H_SZ;
            float acc = 0.f;
#pragma unroll
            for (int p = 0; p < 4; ++p) {
                ushort4 eu = *reinterpret_cast<const ushort4*>(row + p * 256 + lane * 4);
                acc += fast_tanh(bfraw2f(eu.x) + hp[p * 4 + 0]) * wv[p * 4 + 0]
                     + fast_tanh(bfraw2f(eu.y) + hp[p * 4 + 1]) * wv[p * 4 + 1]
                     + fast_tanh(bfraw2f(eu.z) + hp[p * 4 + 2]) * wv[p * 4 + 2]
                     + fast_tanh(bfraw2f(eu.w) + hp[p * 4 + 3]) * wv[p * 4 + 3];
            }
#pragma unroll
            for (int off = 32; off > 0; off >>= 1) acc += __shfl_down(acc, off);
            if (lane == 0) s_e[s] = acc;
        }
        __syncthreads();

        float m = -1e30f;
        for (int s = 0; s < S_SZ; ++s) m = fmaxf(m, s_e[s]);
        float sum = 0.f;
        for (int s = 0; s < S_SZ; ++s) sum += __expf(s_e[s] - m);
        const float inv = 1.0f / sum;

        const ushort4* enc_b = reinterpret_cast<const ushort4*>(enc + (size_t)b * S_SZ * H_SZ);
        float4 acc = make_float4(0.f, 0.f, 0.f, 0.f);
        for (int s = 0; s < S_SZ; ++s) {
            const float a = __expf(s_e[s] - m) * inv;
            ushort4 ev = enc_b[s * 256 + tid];
            acc.x += a * bfraw2f(ev.x); acc.y += a * bfraw2f(ev.y);
            acc.z += a * bfraw2f(ev.z); acc.w += a * bfraw2f(ev.w);
        }
        reinterpret_cast<ushort4*>(x + (size_t)b * XW + DW_SZ)[tid] = cvt4(acc);
    } else {
        const int b = blk - nattn;
        const ushort4* row4 = reinterpret_cast<const ushort4*>(
            reinterpret_cast<const unsigned short*>(hgl) + (size_t)b * NGL + 4096);
        float* orow = outp + (size_t)b * V_SZ;

        float m = -1e30f;
        for (int k = tid; k < V_SZ / 4; k += 256) {
            ushort4 u = row4[k];
            m = fmaxf(m, fmaxf(fmaxf(bfraw2f(u.x), bfraw2f(u.y)), fmaxf(bfraw2f(u.z), bfraw2f(u.w))));
        }
#pragma unroll
        for (int off = 32; off > 0; off >>= 1) m = fmaxf(m, __shfl_down(m, off));
        if (lane == 0) s_red[wave] = m;
        __syncthreads();
        if (tid == 0) s_bc = fmaxf(fmaxf(s_red[0], s_red[1]), fmaxf(s_red[2], s_red[3]));
        __syncthreads();
        m = s_bc;

        float sum = 0.f;
        for (int k = tid; k < V_SZ / 4; k += 256) {
            ushort4 u = row4[k];
            sum += expf(bfraw2f(u.x) - m) + expf(bfraw2f(u.y) - m)
                 + expf(bfraw2f(u.z) - m) + expf(bfraw2f(u.w) - m);
        }
#pragma unroll
        for (int off = 32; off > 0; off >>= 1) sum += __shfl_down(sum, off);
        __syncthreads();
        if (lane == 0) s_red[wave] = sum;
        __syncthreads();
        if (tid == 0) s_bc = logf(s_red[0] + s_red[1] + s_red[2] + s_red[3]) + m;
        __syncthreads();
        const float ls = s_bc;

        for (int k = tid; k < V_SZ / 4; k += 256) {
            ushort4 u = row4[k];
            float4 o = make_float4(bfraw2f(u.x) - ls, bfraw2f(u.y) - ls,
                                   bfraw2f(u.z) - ls, bfraw2f(u.w) - ls);
            reinterpret_cast<float4*>(orow)[k] = o;
        }
    }
}

// ---------------- GRU gate combine ----------------
__global__ __launch_bounds__(256) void gru_gate_kernel(
    const __hip_bfloat16* __restrict__ gi,
    const __hip_bfloat16* __restrict__ hgl,   // gh at +H, row stride NGL
    float* __restrict__ h,
    __hip_bfloat16* __restrict__ h_bf) {
    const int idx = blockIdx.x * 256 + threadIdx.x;
    const int b = idx >> 10;
    const int j = idx & 1023;
    const unsigned short* gib = reinterpret_cast<const unsigned short*>(gi) + (size_t)b * 3 * H_SZ;
    const unsigned short* ghb = reinterpret_cast<const unsigned short*>(hgl) + (size_t)b * NGL + H_SZ;
    const float i_r = bfraw2f(gib[j]), i_z = bfraw2f(gib[H_SZ + j]), i_n = bfraw2f(gib[2 * H_SZ + j]);
    const float h_r = bfraw2f(ghb[j]), h_z = bfraw2f(ghb[H_SZ + j]), h_n = bfraw2f(ghb[2 * H_SZ + j]);
    const float r = fast_sigmoid(i_r + h_r);
    const float z = fast_sigmoid(i_z + h_z);
    const float n = fast_tanh(i_n + r * h_n);
    const float hv = (1.0f - z) * n + z * h[idx];
    h[idx] = hv;
    h_bf[idx] = __float2bfloat16(hv);
}

extern "C" void kernel_launch(void* const* d_in, const int* in_sizes, int n_in,
                              void* d_out, int out_size, void* d_ws, size_t ws_size,
                              hipStream_t stream) {
    const float* enc    = (const float*)d_in[0];
    const float* enc_h  = (const float*)d_in[1];
    const int*   tgt    = (const int*)d_in[2];
    const float* emb    = (const float*)d_in[3];
    const float* w1     = (const float*)d_in[4];
    const float* b1     = (const float*)d_in[5];
    const float* w2     = (const float*)d_in[6];
    const float* w_ih   = (const float*)d_in[7];
    const float* w_hh   = (const float*)d_in[8];
    const float* b_ih   = (const float*)d_in[9];
    const float* b_hh   = (const float*)d_in[10];
    const float* out0_w = (const float*)d_in[11];
    const float* out0_b = (const float*)d_in[12];
    const float* out1_w = (const float*)d_in[13];
    const float* out1_b = (const float*)d_in[14];
    float* out = (float*)d_out;

    char* wp = (char*)d_ws;
    auto carve = [&](size_t bytes) { char* p = wp; wp += (bytes + 255) & ~(size_t)255; return p; };
    __hip_bfloat16* enc_bf  = (__hip_bfloat16*)carve((size_t)B_SZ * S_SZ * H_SZ * 2);
    __hip_bfloat16* encp_bf = (__hip_bfloat16*)carve((size_t)B_SZ * S_SZ * H_SZ * 2);
    __hip_bfloat16* w1a_bf  = (__hip_bfloat16*)carve((size_t)H_SZ * H_SZ * 2);
    __hip_bfloat16* wall0   = (__hip_bfloat16*)carve((size_t)NGL * H_SZ * 2);   // [w1h; whh; o0; pad]
    __hip_bfloat16* wall1   = (__hip_bfloat16*)carve((size_t)NGL * H_SZ * 2);   // [w1h; whh; o1; pad]
    __hip_bfloat16* wih_bf  = (__hip_bfloat16*)carve((size_t)3 * H_SZ * XW * 2);
    float*          bias0   = (float*)carve((size_t)NGL * 4);
    float*          bias1   = (float*)carve((size_t)NGL * 4);
    float*          h       = (float*)carve((size_t)B_SZ * H_SZ * 4);
    __hip_bfloat16* h_bf    = (__hip_bfloat16*)carve((size_t)B_SZ * H_SZ * 2);
    __hip_bfloat16* hgl     = (__hip_bfloat16*)carve((size_t)B_SZ * NGL * 2);   // [hproj|gh|logits|pad]
    __hip_bfloat16* x_bf[3];
    for (int t = 0; t < 3; ++t) x_bf[t] = (__hip_bfloat16*)carve((size_t)B_SZ * XW * 2);
    __hip_bfloat16* gi_bf   = (__hip_bfloat16*)carve((size_t)B_SZ * 3 * H_SZ * 2);

    // --- prep: 2 launches ---
    cast_fast_kernel<<<SBTOT, 256, 0, stream>>>(enc, w1, w_hh, w_ih, out0_w, out1_w,
                                                enc_bf, w1a_bf, wall0, wall1, wih_bf);
    small_prep_kernel<<<4098, 256, 0, stream>>>(emb, tgt, x_bf[0], x_bf[1], x_bf[2],
                                                enc_h, h, h_bf, b1, b_hh, out0_b, out1_b,
                                                bias0, bias1);

    // enc_proj = enc @ w1[:, :H].T   (M=40960, N=1024, K=1024)
    gemm_bt_pipe128<<<(B_SZ * S_SZ / 128) * (H_SZ / 256), 256, 3 * 24576, stream>>>(
        enc_bf, H_SZ, w1a_bf, H_SZ, nullptr, encp_bf, H_SZ, H_SZ / 256, H_SZ);

    // hg(0): first 4096 cols of hgl = h0 @ wcat.T + [b1|b_hh]   (M=1024, N=4096, K=1024)
    gemm_bt_pipe128<<<(B_SZ / 128) * 16, 256, 3 * 24576, stream>>>(
        h_bf, H_SZ, wall0, H_SZ, bias0, hgl, NGL, 16, H_SZ);

    // attn(0) standalone
    attn_ls_kernel<<<B_SZ, 256, 0, stream>>>(enc_bf, encp_bf, hgl, w2, x_bf[0], out, B_SZ);

    for (int t = 0; t < 3; ++t) {
        // gi = x @ w_ih.T + b_ih   (M=1024, N=3072, K=1536)
        gemm_bt_pipe128<<<(B_SZ / 128) * 12, 256, 3 * 24576, stream>>>(
            x_bf[t], XW, wih_bf, XW, b_ih, gi_bf, 3 * H_SZ, 12, XW);

        gru_gate_kernel<<<(B_SZ * H_SZ) / 256, 256, 0, stream>>>(gi_bf, hgl, h, h_bf);

        // hgl = h @ wall_t.T + bias_t : [hg(t+1) | logits(t)]
        // logits weights: t==0 -> o0 (wall0), t==1 -> o1 (wall1), t==2 -> o0 (wall0)
        if (t == 0) {
            gemm_bt_pipe128<<<(B_SZ / 128) * 32, 256, 3 * 24576, stream>>>(
                h_bf, H_SZ, wall0, H_SZ, bias0, hgl, NGL, 32, H_SZ);
        } else if (t == 1) {
            gemm_bt_pipe128<<<(B_SZ / 128) * 32, 256, 3 * 24576, stream>>>(
                h_bf, H_SZ, wall1, H_SZ, bias1, hgl, NGL, 32, H_SZ);
        } else {
            // t==2: logits only, with out0_w / out0_b (wall0 rows 4096..8191)
            gemm_bt_pipe128<<<(B_SZ / 128) * 16, 256, 3 * 24576, stream>>>(
                h_bf, H_SZ, wall0 + (size_t)4 * H_SZ * H_SZ, H_SZ, bias0 + 4 * H_SZ,
                hgl + 4 * H_SZ, NGL, 16, H_SZ);
        }

        // fused: log-softmax(t) [+ attention(t+1) when t<2]
        float* outp = out + (size_t)t * B_SZ * V_SZ;
        if (t < 2) {
            attn_ls_kernel<<<2 * B_SZ, 256, 0, stream>>>(enc_bf, encp_bf, hgl, w2, x_bf[t + 1],
                                                         outp, B_SZ);
        } else {
            attn_ls_kernel<<<B_SZ, 256, 0, stream>>>(enc_bf, encp_bf, hgl, w2, x_bf[0],
                                                     outp, 0);
        }
    }
}

// Round 14
// 491.717 us; speedup vs baseline: 1.1878x; 1.0429x over previous
//
#include <hip/hip_runtime.h>
#include <hip/hip_bf16.h>
#include <math.h>

#define B_SZ 1024
#define S_SZ 40
#define H_SZ 1024
#define DW_SZ 512
#define V_SZ 4000
#define XW (DW_SZ + H_SZ)      // 1536
#define NGL 8192               // hgl row: [hproj(1024) | gh(3072) | logits(4000) | pad(96)]

typedef __bf16 bf16x8 __attribute__((ext_vector_type(8)));
typedef float f32x4 __attribute__((ext_vector_type(4)));

__device__ __forceinline__ float fast_tanh(float x) {
    return 1.0f - 2.0f / (1.0f + __expf(2.0f * x));
}
__device__ __forceinline__ float fast_sigmoid(float x) {
    return 1.0f / (1.0f + __expf(-x));
}
__device__ __forceinline__ float bfraw2f(unsigned short u) {
    return __uint_as_float(((unsigned)u) << 16);
}
__device__ __forceinline__ ushort4 cvt4(float4 v) {
    union { ushort4 u; __hip_bfloat16 h[4]; } o;
    o.h[0] = __float2bfloat16(v.x); o.h[1] = __float2bfloat16(v.y);
    o.h[2] = __float2bfloat16(v.z); o.h[3] = __float2bfloat16(v.w);
    return o.u;
}

#define GLL16(gp, lp)                                                                \
    __builtin_amdgcn_global_load_lds((const __attribute__((address_space(1))) void*)(gp), \
                                     (__attribute__((address_space(3))) void*)(lp), 16, 0, 0)

// ========== 128x256 tile, BK=32, 3-slot counted-vmcnt pipelined GEMM ==========
// v2: 512 threads (8 waves, wave-tile 64x64), 2 blocks/CU -> 16 waves/CU.
// Same tile / LDS slots / swizzle / counted-vmcnt discipline as the proven 256-thread
// version (846 TF, 0 conflicts); only thread-count & per-thread GLL (6->3, vmcnt 6->3) change.
// Requirements: M%128==0, N%256==0, K%32==0, K/32>=3, grid%8==0. bf16 out, optional bias.
__global__ __launch_bounds__(512, 2) void gemm_bt_pipe128(
    const __hip_bfloat16* __restrict__ A, int lda,
    const __hip_bfloat16* __restrict__ W, int ldw,
    const float* __restrict__ bias,
    __hip_bfloat16* __restrict__ C, int ldc,
    int nbx, int K) {
    extern __shared__ char smem[];   // 3 * 24576 bytes
    const int tid = threadIdx.x;
    const int lane = tid & 63;
    const int wave = tid >> 6;           // 0..7
    const int wm = wave >> 2, wn = wave & 3;
    const int fr = lane & 15, fq = lane >> 4;

    int bid = blockIdx.x;
    { const int cpx = gridDim.x >> 3; bid = (bid & 7) * cpx + (bid >> 3); }  // XCD swizzle
    const int by = bid / nbx;
    const int bm = by * 128;
    const int bn = (bid - by * nbx) * 256;

    // staging: rows of 32 bf16 (64B = 4 slots); chunk c -> row c>>2, phys slot c&3,
    // pre-swizzled source slot (c&3)^((row>>1)&3). Thread owns: A chunk tid,
    // B chunks tid and tid+512 (row +128; (row>>1)&3 invariant, 64%4==0).
    const int r0 = tid >> 2;                       // 0..127
    const int s0 = (tid & 3) ^ ((tid >> 3) & 3);
    const __hip_bfloat16* gA0 = A + (size_t)(bm + r0) * lda + s0 * 8;
    const __hip_bfloat16* gW0 = W + (size_t)(bn + r0) * ldw + s0 * 8;
    const __hip_bfloat16* gW1 = W + (size_t)(bn + r0 + 128) * ldw + s0 * 8;
    const int dst0 = tid * 16;

    // ds_read byte offsets within slot: A at +0 (8KB), B at +8192 (16KB)
    int aoff[4], boff[4];
#pragma unroll
    for (int mi = 0; mi < 4; ++mi) {
        const int row = wm * 64 + mi * 16 + fr;
        aoff[mi] = row * 64 + ((fq ^ ((row >> 1) & 3)) << 4);
    }
#pragma unroll
    for (int ni = 0; ni < 4; ++ni) {
        const int col = wn * 64 + ni * 16 + fr;
        boff[ni] = 8192 + col * 64 + ((fq ^ ((col >> 1) & 3)) << 4);
    }

    const int NT = K >> 5;
    f32x4 acc[4][4] = {};

#define STAGE_T(t)                                                    \
    do {                                                              \
        char* sb = smem + ((t) % 3) * 24576;                          \
        const int kk = (t) << 5;                                      \
        GLL16(gA0 + kk, sb + dst0);                                   \
        GLL16(gW0 + kk, sb + 8192 + dst0);                            \
        GLL16(gW1 + kk, sb + 8192 + dst0 + 8192);                     \
    } while (0)

    STAGE_T(0);
    STAGE_T(1);
    __builtin_amdgcn_sched_barrier(0);
    asm volatile("s_waitcnt vmcnt(3)" ::: "memory");   // tile 0 landed (tile 1 in flight)
    __builtin_amdgcn_s_barrier();
    __builtin_amdgcn_sched_barrier(0);

    for (int t = 0; t < NT; ++t) {
        const char* sb = smem + (t % 3) * 24576;
        bf16x8 af[4], bg[4];
#pragma unroll
        for (int ni = 0; ni < 4; ++ni) bg[ni] = *reinterpret_cast<const bf16x8*>(sb + boff[ni]);
#pragma unroll
        for (int mi = 0; mi < 4; ++mi) af[mi] = *reinterpret_cast<const bf16x8*>(sb + aoff[mi]);

        if (t + 2 < NT) STAGE_T(t + 2);

        __builtin_amdgcn_s_setprio(1);
#pragma unroll
        for (int mi = 0; mi < 4; ++mi)
#pragma unroll
            for (int ni = 0; ni < 4; ++ni)
                acc[mi][ni] = __builtin_amdgcn_mfma_f32_16x16x32_bf16(af[mi], bg[ni], acc[mi][ni], 0, 0, 0);
        __builtin_amdgcn_s_setprio(0);

        if (t != NT - 1) {
            __builtin_amdgcn_sched_barrier(0);
            if (t + 2 < NT) asm volatile("s_waitcnt vmcnt(3)" ::: "memory");  // tile t+1 landed
            else            asm volatile("s_waitcnt vmcnt(0)" ::: "memory");
            __builtin_amdgcn_s_barrier();
            __builtin_amdgcn_sched_barrier(0);
        }
    }
#undef STAGE_T

    // epilogue: C/D layout col=lane&15, row=(lane>>4)*4+reg
#pragma unroll
    for (int ni = 0; ni < 4; ++ni) {
        const int col = bn + wn * 64 + ni * 16 + fr;
        const float bb = bias ? bias[col] : 0.0f;
#pragma unroll
        for (int mi = 0; mi < 4; ++mi) {
            const int row0 = bm + wm * 64 + mi * 16 + fq * 4;
#pragma unroll
            for (int r = 0; r < 4; ++r)
                C[(size_t)(row0 + r) * ldc + col] = __float2bfloat16(acc[mi][ni][r] + bb);
        }
    }
}

// ---------------- fast cast v2: block-uniform segment, straight-line 4-load/4-store ----------------
#define SB0 0                    // enc        (10240 blocks, flat)
#define SB1 10240                // w1a        (256, strided from w1 cols [0,256))
#define SB2 10496                // w1h dual   (256, strided from w1 cols [256,512) -> wall0+wall1)
#define SB3 10752                // whh dual   (768, flat -> wall0+wall1 @ +262144 u4)
#define SB4 11520                // wih        (1152, flat)
#define SB5 12672                // o0         (1000, flat -> wall0 @ +1048576 u4)
#define SB6 13672                // o1         (1000, flat -> wall1 @ +1048576 u4)
#define SB7 14672                // wall0 pad zero (24 blocks @ u4 2072576)
#define SB8 14696                // wall1 pad zero (24)
#define SBTOT 14720
__global__ __launch_bounds__(256) void cast_fast_kernel(
    const float* __restrict__ enc, const float* __restrict__ w1,
    const float* __restrict__ whh, const float* __restrict__ wih,
    const float* __restrict__ o0, const float* __restrict__ o1,
    __hip_bfloat16* __restrict__ enc_bf, __hip_bfloat16* __restrict__ w1a_bf,
    __hip_bfloat16* __restrict__ wall0, __hip_bfloat16* __restrict__ wall1,
    __hip_bfloat16* __restrict__ wih_bf) {
    const int blk = blockIdx.x;
    const int tid = threadIdx.x;
    ushort4* w0u = reinterpret_cast<ushort4*>(wall0);
    ushort4* w1u = reinterpret_cast<ushort4*>(wall1);

    if (blk < SB1) {                      // enc (flat)
        const int li = blk * 1024 + tid;
        const float4* s = reinterpret_cast<const float4*>(enc);
        float4 v0 = s[li], v1 = s[li + 256], v2 = s[li + 512], v3 = s[li + 768];
        ushort4* d = reinterpret_cast<ushort4*>(enc_bf);
        d[li] = cvt4(v0); d[li + 256] = cvt4(v1); d[li + 512] = cvt4(v2); d[li + 768] = cvt4(v3);
    } else if (blk < SB2) {               // w1[:, :H] (strided)
        const int r0 = (blk - SB1) * 4;
        const float4* s = reinterpret_cast<const float4*>(w1);
        float4 v0 = s[(r0 + 0) * 512 + tid], v1 = s[(r0 + 1) * 512 + tid],
               v2 = s[(r0 + 2) * 512 + tid], v3 = s[(r0 + 3) * 512 + tid];
        ushort4* d = reinterpret_cast<ushort4*>(w1a_bf);
        const int li = r0 * 256 + tid;
        d[li] = cvt4(v0); d[li + 256] = cvt4(v1); d[li + 512] = cvt4(v2); d[li + 768] = cvt4(v3);
    } else if (blk < SB3) {               // w1[:, H:] (strided, dual write)
        const int r0 = (blk - SB2) * 4;
        const float4* s = reinterpret_cast<const float4*>(w1);
        ushort4 u0 = cvt4(s[(r0 + 0) * 512 + 256 + tid]), u1 = cvt4(s[(r0 + 1) * 512 + 256 + tid]),
                u2 = cvt4(s[(r0 + 2) * 512 + 256 + tid]), u3 = cvt4(s[(r0 + 3) * 512 + 256 + tid]);
        const int li = r0 * 256 + tid;
        w0u[li] = u0; w0u[li + 256] = u1; w0u[li + 512] = u2; w0u[li + 768] = u3;
        w1u[li] = u0; w1u[li + 256] = u1; w1u[li + 512] = u2; w1u[li + 768] = u3;
    } else if (blk < SB4) {               // whh (flat, dual write)
        const int li = (blk - SB3) * 1024 + tid;
        const float4* s = reinterpret_cast<const float4*>(whh);
        ushort4 u0 = cvt4(s[li]), u1 = cvt4(s[li + 256]), u2 = cvt4(s[li + 512]), u3 = cvt4(s[li + 768]);
        w0u[262144 + li] = u0; w0u[262144 + li + 256] = u1;
        w0u[262144 + li + 512] = u2; w0u[262144 + li + 768] = u3;
        w1u[262144 + li] = u0; w1u[262144 + li + 256] = u1;
        w1u[262144 + li + 512] = u2; w1u[262144 + li + 768] = u3;
    } else if (blk < SB5) {               // wih (flat)
        const int li = (blk - SB4) * 1024 + tid;
        const float4* s = reinterpret_cast<const float4*>(wih);
        float4 v0 = s[li], v1 = s[li + 256], v2 = s[li + 512], v3 = s[li + 768];
        ushort4* d = reinterpret_cast<ushort4*>(wih_bf);
        d[li] = cvt4(v0); d[li + 256] = cvt4(v1); d[li + 512] = cvt4(v2); d[li + 768] = cvt4(v3);
    } else if (blk < SB6) {               // o0 (flat)
        const int li = (blk - SB5) * 1024 + tid;
        const float4* s = reinterpret_cast<const float4*>(o0);
        float4 v0 = s[li], v1 = s[li + 256], v2 = s[li + 512], v3 = s[li + 768];
        w0u[1048576 + li] = cvt4(v0); w0u[1048576 + li + 256] = cvt4(v1);
        w0u[1048576 + li + 512] = cvt4(v2); w0u[1048576 + li + 768] = cvt4(v3);
    } else if (blk < SB7) {               // o1 (flat)
        const int li = (blk - SB6) * 1024 + tid;
        const float4* s = reinterpret_cast<const float4*>(o1);
        float4 v0 = s[li], v1 = s[li + 256], v2 = s[li + 512], v3 = s[li + 768];
        w1u[1048576 + li] = cvt4(v0); w1u[1048576 + li + 256] = cvt4(v1);
        w1u[1048576 + li + 512] = cvt4(v2); w1u[1048576 + li + 768] = cvt4(v3);
    } else {                              // zero pad rows of wall0 / wall1
        const ushort4 z = make_ushort4(0, 0, 0, 0);
        if (blk < SB8) {
            const int li = 2072576 + (blk - SB7) * 1024 + tid;
            w0u[li] = z; w0u[li + 256] = z; w0u[li + 512] = z; w0u[li + 768] = z;
        } else {
            const int li = 2072576 + (blk - SB8) * 1024 + tid;
            w1u[li] = z; w1u[li + 256] = z; w1u[li + 512] = z; w1u[li + 768] = z;
        }
    }
}

// ---------------- small prep: emb prefill (<3072), h init (3072..4095), bias0/bias1 (4096/4097) ----------------
__global__ __launch_bounds__(256) void small_prep_kernel(
    const float* __restrict__ emb, const int* __restrict__ targets,
    __hip_bfloat16* __restrict__ x0, __hip_bfloat16* __restrict__ x1, __hip_bfloat16* __restrict__ x2,
    const float* __restrict__ enc_h, float* __restrict__ h, __hip_bfloat16* __restrict__ h_bf,
    const float* __restrict__ b1, const float* __restrict__ b_hh,
    const float* __restrict__ o0b, const float* __restrict__ o1b,
    float* __restrict__ bias0, float* __restrict__ bias1) {
    const int blk = blockIdx.x;
    const int tid = threadIdx.x;
    if (blk < 3072) {
        if (tid >= 128) return;
        const int t = blk >> 10;
        const int b = blk & 1023;
        int it; __hip_bfloat16* x;
        if (t == 0) { it = 0; x = x0; }
        else if (t == 1) { it = targets[b] + 1; x = x1; }
        else { it = targets[B_SZ + b] + 36; x = x2; }
        float4 v = reinterpret_cast<const float4*>(emb + (size_t)it * DW_SZ)[tid];
        reinterpret_cast<ushort4*>(x + (size_t)b * XW)[tid] = cvt4(v);
    } else if (blk < 4096) {
        const int i = (blk - 3072) * 256 + tid;
        const float4 v = reinterpret_cast<const float4*>(enc_h)[i];
        reinterpret_cast<float4*>(h)[i] = v;
        reinterpret_cast<ushort4*>(h_bf)[i] = cvt4(v);
    } else {
        float* bt = (blk == 4096) ? bias0 : bias1;
        const float* ob = (blk == 4096) ? o0b : o1b;
        for (int j = tid; j < NGL; j += 256) {
            float v;
            if (j < H_SZ) v = b1[j];
            else if (j < 4 * H_SZ) v = b_hh[j - H_SZ];
            else if (j < 4 * H_SZ + V_SZ) v = ob[j - 4 * H_SZ];
            else v = 0.0f;
            bt[j] = v;
        }
    }
}

// ---------------- fused: blocks [0,nattn) = attention; rest = log-softmax ----------------
__global__ __launch_bounds__(256) void attn_ls_kernel(
    const __hip_bfloat16* __restrict__ enc,
    const __hip_bfloat16* __restrict__ enc_proj,
    const __hip_bfloat16* __restrict__ hgl,    // [B][NGL]; hproj at +0, logits at +4096
    const float* __restrict__ w2,
    __hip_bfloat16* __restrict__ x,
    float* __restrict__ outp,
    int nattn) {
    const int blk = blockIdx.x;
    const int tid = threadIdx.x;
    const int lane = tid & 63, wave = tid >> 6;
    __shared__ float s_e[S_SZ];
    __shared__ float s_red[4];
    __shared__ float s_bc;

    if (blk < nattn) {
        const int b = blk;
        float hp[16], wv[16];
        const unsigned short* hgrow = reinterpret_cast<const unsigned short*>(hgl) + (size_t)b * NGL;
#pragma unroll
        for (int p = 0; p < 4; ++p) {
            const int base = p * 256 + lane * 4;
            ushort4 hu = *reinterpret_cast<const ushort4*>(hgrow + base);
            float4 wq = *reinterpret_cast<const float4*>(w2 + base);
            hp[p * 4 + 0] = bfraw2f(hu.x); hp[p * 4 + 1] = bfraw2f(hu.y);
            hp[p * 4 + 2] = bfraw2f(hu.z); hp[p * 4 + 3] = bfraw2f(hu.w);
            wv[p * 4 + 0] = wq.x; wv[p * 4 + 1] = wq.y;
            wv[p * 4 + 2] = wq.z; wv[p * 4 + 3] = wq.w;
        }

        const unsigned short* ep0 = reinterpret_cast<const unsigned short*>(enc_proj) + (size_t)b * S_SZ * H_SZ;
#pragma unroll 2
        for (int i = 0; i < 10; ++i) {
            const int s = wave + 4 * i;
            const unsigned short* row = ep0 + (size_t)s * H_SZ;
            float acc = 0.f;
#pragma unroll
            for (int p = 0; p < 4; ++p) {
                ushort4 eu = *reinterpret_cast<const ushort4*>(row + p * 256 + lane * 4);
                acc += fast_tanh(bfraw2f(eu.x) + hp[p * 4 + 0]) * wv[p * 4 + 0]
                     + fast_tanh(bfraw2f(eu.y) + hp[p * 4 + 1]) * wv[p * 4 + 1]
                     + fast_tanh(bfraw2f(eu.z) + hp[p * 4 + 2]) * wv[p * 4 + 2]
                     + fast_tanh(bfraw2f(eu.w) + hp[p * 4 + 3]) * wv[p * 4 + 3];
            }
#pragma unroll
            for (int off = 32; off > 0; off >>= 1) acc += __shfl_down(acc, off);
            if (lane == 0) s_e[s] = acc;
        }
        __syncthreads();

        float m = -1e30f;
        for (int s = 0; s < S_SZ; ++s) m = fmaxf(m, s_e[s]);
        float sum = 0.f;
        for (int s = 0; s < S_SZ; ++s) sum += __expf(s_e[s] - m);
        const float inv = 1.0f / sum;

        const ushort4* enc_b = reinterpret_cast<const ushort4*>(enc + (size_t)b * S_SZ * H_SZ);
        float4 acc = make_float4(0.f, 0.f, 0.f, 0.f);
        for (int s = 0; s < S_SZ; ++s) {
            const float a = __expf(s_e[s] - m) * inv;
            ushort4 ev = enc_b[s * 256 + tid];
            acc.x += a * bfraw2f(ev.x); acc.y += a * bfraw2f(ev.y);
            acc.z += a * bfraw2f(ev.z); acc.w += a * bfraw2f(ev.w);
        }
        reinterpret_cast<ushort4*>(x + (size_t)b * XW + DW_SZ)[tid] = cvt4(acc);
    } else {
        const int b = blk - nattn;
        const ushort4* row4 = reinterpret_cast<const ushort4*>(
            reinterpret_cast<const unsigned short*>(hgl) + (size_t)b * NGL + 4096);
        float* orow = outp + (size_t)b * V_SZ;

        float m = -1e30f;
        for (int k = tid; k < V_SZ / 4; k += 256) {
            ushort4 u = row4[k];
            m = fmaxf(m, fmaxf(fmaxf(bfraw2f(u.x), bfraw2f(u.y)), fmaxf(bfraw2f(u.z), bfraw2f(u.w))));
        }
#pragma unroll
        for (int off = 32; off > 0; off >>= 1) m = fmaxf(m, __shfl_down(m, off));
        if (lane == 0) s_red[wave] = m;
        __syncthreads();
        if (tid == 0) s_bc = fmaxf(fmaxf(s_red[0], s_red[1]), fmaxf(s_red[2], s_red[3]));
        __syncthreads();
        m = s_bc;

        float sum = 0.f;
        for (int k = tid; k < V_SZ / 4; k += 256) {
            ushort4 u = row4[k];
            sum += expf(bfraw2f(u.x) - m) + expf(bfraw2f(u.y) - m)
                 + expf(bfraw2f(u.z) - m) + expf(bfraw2f(u.w) - m);
        }
#pragma unroll
        for (int off = 32; off > 0; off >>= 1) sum += __shfl_down(sum, off);
        __syncthreads();
        if (lane == 0) s_red[wave] = sum;
        __syncthreads();
        if (tid == 0) s_bc = logf(s_red[0] + s_red[1] + s_red[2] + s_red[3]) + m;
        __syncthreads();
        const float ls = s_bc;

        for (int k = tid; k < V_SZ / 4; k += 256) {
            ushort4 u = row4[k];
            float4 o = make_float4(bfraw2f(u.x) - ls, bfraw2f(u.y) - ls,
                                   bfraw2f(u.z) - ls, bfraw2f(u.w) - ls);
            reinterpret_cast<float4*>(orow)[k] = o;
        }
    }
}

// ---------------- GRU gate combine ----------------
__global__ __launch_bounds__(256) void gru_gate_kernel(
    const __hip_bfloat16* __restrict__ gi,
    const __hip_bfloat16* __restrict__ hgl,   // gh at +H, row stride NGL
    float* __restrict__ h,
    __hip_bfloat16* __restrict__ h_bf) {
    const int idx = blockIdx.x * 256 + threadIdx.x;
    const int b = idx >> 10;
    const int j = idx & 1023;
    const unsigned short* gib = reinterpret_cast<const unsigned short*>(gi) + (size_t)b * 3 * H_SZ;
    const unsigned short* ghb = reinterpret_cast<const unsigned short*>(hgl) + (size_t)b * NGL + H_SZ;
    const float i_r = bfraw2f(gib[j]), i_z = bfraw2f(gib[H_SZ + j]), i_n = bfraw2f(gib[2 * H_SZ + j]);
    const float h_r = bfraw2f(ghb[j]), h_z = bfraw2f(ghb[H_SZ + j]), h_n = bfraw2f(ghb[2 * H_SZ + j]);
    const float r = fast_sigmoid(i_r + h_r);
    const float z = fast_sigmoid(i_z + h_z);
    const float n = fast_tanh(i_n + r * h_n);
    const float hv = (1.0f - z) * n + z * h[idx];
    h[idx] = hv;
    h_bf[idx] = __float2bfloat16(hv);
}

extern "C" void kernel_launch(void* const* d_in, const int* in_sizes, int n_in,
                              void* d_out, int out_size, void* d_ws, size_t ws_size,
                              hipStream_t stream) {
    const float* enc    = (const float*)d_in[0];
    const float* enc_h  = (const float*)d_in[1];
    const int*   tgt    = (const int*)d_in[2];
    const float* emb    = (const float*)d_in[3];
    const float* w1     = (const float*)d_in[4];
    const float* b1     = (const float*)d_in[5];
    const float* w2     = (const float*)d_in[6];
    const float* w_ih   = (const float*)d_in[7];
    const float* w_hh   = (const float*)d_in[8];
    const float* b_ih   = (const float*)d_in[9];
    const float* b_hh   = (const float*)d_in[10];
    const float* out0_w = (const float*)d_in[11];
    const float* out0_b = (const float*)d_in[12];
    const float* out1_w = (const float*)d_in[13];
    const float* out1_b = (const float*)d_in[14];
    float* out = (float*)d_out;

    char* wp = (char*)d_ws;
    auto carve = [&](size_t bytes) { char* p = wp; wp += (bytes + 255) & ~(size_t)255; return p; };
    __hip_bfloat16* enc_bf  = (__hip_bfloat16*)carve((size_t)B_SZ * S_SZ * H_SZ * 2);
    __hip_bfloat16* encp_bf = (__hip_bfloat16*)carve((size_t)B_SZ * S_SZ * H_SZ * 2);
    __hip_bfloat16* w1a_bf  = (__hip_bfloat16*)carve((size_t)H_SZ * H_SZ * 2);
    __hip_bfloat16* wall0   = (__hip_bfloat16*)carve((size_t)NGL * H_SZ * 2);   // [w1h; whh; o0; pad]
    __hip_bfloat16* wall1   = (__hip_bfloat16*)carve((size_t)NGL * H_SZ * 2);   // [w1h; whh; o1; pad]
    __hip_bfloat16* wih_bf  = (__hip_bfloat16*)carve((size_t)3 * H_SZ * XW * 2);
    float*          bias0   = (float*)carve((size_t)NGL * 4);
    float*          bias1   = (float*)carve((size_t)NGL * 4);
    float*          h       = (float*)carve((size_t)B_SZ * H_SZ * 4);
    __hip_bfloat16* h_bf    = (__hip_bfloat16*)carve((size_t)B_SZ * H_SZ * 2);
    __hip_bfloat16* hgl     = (__hip_bfloat16*)carve((size_t)B_SZ * NGL * 2);   // [hproj|gh|logits|pad]
    __hip_bfloat16* x_bf[3];
    for (int t = 0; t < 3; ++t) x_bf[t] = (__hip_bfloat16*)carve((size_t)B_SZ * XW * 2);
    __hip_bfloat16* gi_bf   = (__hip_bfloat16*)carve((size_t)B_SZ * 3 * H_SZ * 2);

    // --- prep: 2 launches ---
    cast_fast_kernel<<<SBTOT, 256, 0, stream>>>(enc, w1, w_hh, w_ih, out0_w, out1_w,
                                                enc_bf, w1a_bf, wall0, wall1, wih_bf);
    small_prep_kernel<<<4098, 256, 0, stream>>>(emb, tgt, x_bf[0], x_bf[1], x_bf[2],
                                                enc_h, h, h_bf, b1, b_hh, out0_b, out1_b,
                                                bias0, bias1);

    // enc_proj = enc @ w1[:, :H].T   (M=40960, N=1024, K=1024)
    gemm_bt_pipe128<<<(B_SZ * S_SZ / 128) * (H_SZ / 256), 512, 3 * 24576, stream>>>(
        enc_bf, H_SZ, w1a_bf, H_SZ, nullptr, encp_bf, H_SZ, H_SZ / 256, H_SZ);

    // hg(0): first 4096 cols of hgl = h0 @ wcat.T + [b1|b_hh]   (M=1024, N=4096, K=1024)
    gemm_bt_pipe128<<<(B_SZ / 128) * 16, 512, 3 * 24576, stream>>>(
        h_bf, H_SZ, wall0, H_SZ, bias0, hgl, NGL, 16, H_SZ);

    // attn(0) standalone
    attn_ls_kernel<<<B_SZ, 256, 0, stream>>>(enc_bf, encp_bf, hgl, w2, x_bf[0], out, B_SZ);

    for (int t = 0; t < 3; ++t) {
        // gi = x @ w_ih.T + b_ih   (M=1024, N=3072, K=1536)
        gemm_bt_pipe128<<<(B_SZ / 128) * 12, 512, 3 * 24576, stream>>>(
            x_bf[t], XW, wih_bf, XW, b_ih, gi_bf, 3 * H_SZ, 12, XW);

        gru_gate_kernel<<<(B_SZ * H_SZ) / 256, 256, 0, stream>>>(gi_bf, hgl, h, h_bf);

        // hgl = h @ wall_t.T + bias_t : [hg(t+1) | logits(t)]
        // logits weights: t==0 -> o0 (wall0), t==1 -> o1 (wall1), t==2 -> o0 (wall0)
        if (t == 0) {
            gemm_bt_pipe128<<<(B_SZ / 128) * 32, 512, 3 * 24576, stream>>>(
                h_bf, H_SZ, wall0, H_SZ, bias0, hgl, NGL, 32, H_SZ);
        } else if (t == 1) {
            gemm_bt_pipe128<<<(B_SZ / 128) * 32, 512, 3 * 24576, stream>>>(
                h_bf, H_SZ, wall1, H_SZ, bias1, hgl, NGL, 32, H_SZ);
        } else {
            // t==2: logits only, with out0_w / out0_b (wall0 rows 4096..8191)
            gemm_bt_pipe128<<<(B_SZ / 128) * 16, 512, 3 * 24576, stream>>>(
                h_bf, H_SZ, wall0 + (size_t)4 * H_SZ * H_SZ, H_SZ, bias0 + 4 * H_SZ,
                hgl + 4 * H_SZ, NGL, 16, H_SZ);
        }

        // fused: log-softmax(t) [+ attention(t+1) when t<2]
        float* outp = out + (size_t)t * B_SZ * V_SZ;
        if (t < 2) {
            attn_ls_kernel<<<2 * B_SZ, 256, 0, stream>>>(enc_bf, encp_bf, hgl, w2, x_bf[t + 1],
                                                         outp, B_SZ);
        } else {
            attn_ls_kernel<<<B_SZ, 256, 0, stream>>>(enc_bf, encp_bf, hgl, w2, x_bf[0],
                                                     outp, 0);
        }
    }
}

// Round 15
// 489.985 us; speedup vs baseline: 1.1920x; 1.0035x over previous
//
#include <hip/hip_runtime.h>
#include <hip/hip_bf16.h>
#include <math.h>

#define B_SZ 1024
#define S_SZ 40
#define H_SZ 1024
#define DW_SZ 512
#define V_SZ 4000
#define XW (DW_SZ + H_SZ)      // 1536
#define NGL 8192               // hgl row: [hproj(1024) | gh(3072) | logits(4000) | pad(96)]

typedef __bf16 bf16x8 __attribute__((ext_vector_type(8)));
typedef float f32x4 __attribute__((ext_vector_type(4)));

__device__ __forceinline__ float fast_tanh(float x) {
    return 1.0f - 2.0f / (1.0f + __expf(2.0f * x));
}
__device__ __forceinline__ float fast_sigmoid(float x) {
    return 1.0f / (1.0f + __expf(-x));
}
__device__ __forceinline__ float bfraw2f(unsigned short u) {
    return __uint_as_float(((unsigned)u) << 16);
}
__device__ __forceinline__ ushort4 cvt4(float4 v) {
    union { ushort4 u; __hip_bfloat16 h[4]; } o;
    o.h[0] = __float2bfloat16(v.x); o.h[1] = __float2bfloat16(v.y);
    o.h[2] = __float2bfloat16(v.z); o.h[3] = __float2bfloat16(v.w);
    return o.u;
}

#define GLL16(gp, lp)                                                                \
    __builtin_amdgcn_global_load_lds((const __attribute__((address_space(1))) void*)(gp), \
                                     (__attribute__((address_space(3))) void*)(lp), 16, 0, 0)

// ========== v1: 128x256 tile, BK=32, 3-slot counted-vmcnt GEMM, 256 thr, 2 blocks/CU ==========
// Proven 103 us on enc_proj (846 TF, 0 conflicts). Best for large-M shapes.
__global__ __launch_bounds__(256, 2) void gemm_bt_pipe128_v1(
    const __hip_bfloat16* __restrict__ A, int lda,
    const __hip_bfloat16* __restrict__ W, int ldw,
    const float* __restrict__ bias,
    __hip_bfloat16* __restrict__ C, int ldc,
    int nbx, int K) {
    extern __shared__ char smem[];   // 3 * 24576 bytes
    const int tid = threadIdx.x;
    const int lane = tid & 63;
    const int wave = tid >> 6;
    const int wm = wave >> 1, wn = wave & 1;
    const int fr = lane & 15, fq = lane >> 4;

    int bid = blockIdx.x;
    { const int cpx = gridDim.x >> 3; bid = (bid & 7) * cpx + (bid >> 3); }  // XCD swizzle
    const int by = bid / nbx;
    const int bm = by * 128;
    const int bn = (bid - by * nbx) * 256;

    const int r0 = tid >> 2;
    const int s0 = (tid & 3) ^ ((tid >> 3) & 3);
    const __hip_bfloat16* gA0 = A + (size_t)(bm + r0) * lda + s0 * 8;
    const __hip_bfloat16* gA1 = A + (size_t)(bm + r0 + 64) * lda + s0 * 8;
    const __hip_bfloat16* gW0 = W + (size_t)(bn + r0) * ldw + s0 * 8;
    const __hip_bfloat16* gW1 = W + (size_t)(bn + r0 + 64) * ldw + s0 * 8;
    const __hip_bfloat16* gW2 = W + (size_t)(bn + r0 + 128) * ldw + s0 * 8;
    const __hip_bfloat16* gW3 = W + (size_t)(bn + r0 + 192) * ldw + s0 * 8;
    const int dst0 = tid * 16;

    int aoff[4], boff[8];
#pragma unroll
    for (int mi = 0; mi < 4; ++mi) {
        const int row = wm * 64 + mi * 16 + fr;
        aoff[mi] = row * 64 + ((fq ^ ((row >> 1) & 3)) << 4);
    }
#pragma unroll
    for (int ni = 0; ni < 8; ++ni) {
        const int col = wn * 128 + ni * 16 + fr;
        boff[ni] = 8192 + col * 64 + ((fq ^ ((col >> 1) & 3)) << 4);
    }

    const int NT = K >> 5;
    f32x4 acc[4][8] = {};

#define STAGE_T(t)                                                    \
    do {                                                              \
        char* sb = smem + ((t) % 3) * 24576;                          \
        const int kk = (t) << 5;                                      \
        GLL16(gA0 + kk, sb + dst0);                                   \
        GLL16(gA1 + kk, sb + dst0 + 4096);                            \
        GLL16(gW0 + kk, sb + 8192 + dst0);                            \
        GLL16(gW1 + kk, sb + 8192 + dst0 + 4096);                     \
        GLL16(gW2 + kk, sb + 8192 + dst0 + 8192);                     \
        GLL16(gW3 + kk, sb + 8192 + dst0 + 12288);                    \
    } while (0)

    STAGE_T(0);
    STAGE_T(1);
    __builtin_amdgcn_sched_barrier(0);
    asm volatile("s_waitcnt vmcnt(6)" ::: "memory");
    __builtin_amdgcn_s_barrier();
    __builtin_amdgcn_sched_barrier(0);

    for (int t = 0; t < NT; ++t) {
        const char* sb = smem + (t % 3) * 24576;
        bf16x8 af[4], bg[8];
#pragma unroll
        for (int ni = 0; ni < 8; ++ni) bg[ni] = *reinterpret_cast<const bf16x8*>(sb + boff[ni]);
#pragma unroll
        for (int mi = 0; mi < 4; ++mi) af[mi] = *reinterpret_cast<const bf16x8*>(sb + aoff[mi]);

        if (t + 2 < NT) STAGE_T(t + 2);

        __builtin_amdgcn_s_setprio(1);
#pragma unroll
        for (int mi = 0; mi < 4; ++mi)
#pragma unroll
            for (int ni = 0; ni < 8; ++ni)
                acc[mi][ni] = __builtin_amdgcn_mfma_f32_16x16x32_bf16(af[mi], bg[ni], acc[mi][ni], 0, 0, 0);
        __builtin_amdgcn_s_setprio(0);

        if (t != NT - 1) {
            __builtin_amdgcn_sched_barrier(0);
            if (t + 2 < NT) asm volatile("s_waitcnt vmcnt(6)" ::: "memory");
            else            asm volatile("s_waitcnt vmcnt(0)" ::: "memory");
            __builtin_amdgcn_s_barrier();
            __builtin_amdgcn_sched_barrier(0);
        }
    }
#undef STAGE_T

#pragma unroll
    for (int ni = 0; ni < 8; ++ni) {
        const int col = bn + wn * 128 + ni * 16 + fr;
        const float bb = bias ? bias[col] : 0.0f;
#pragma unroll
        for (int mi = 0; mi < 4; ++mi) {
            const int row0 = bm + wm * 64 + mi * 16 + fq * 4;
#pragma unroll
            for (int r = 0; r < 4; ++r)
                C[(size_t)(row0 + r) * ldc + col] = __float2bfloat16(acc[mi][ni][r] + bb);
        }
    }
}

// ========== v2: same tile/ring, 512 threads (8 waves, 64x64 wave-tile), 16 waves/CU ==========
// Measured better on the small M=1024 per-step shapes.
__global__ __launch_bounds__(512, 2) void gemm_bt_pipe128_v2(
    const __hip_bfloat16* __restrict__ A, int lda,
    const __hip_bfloat16* __restrict__ W, int ldw,
    const float* __restrict__ bias,
    __hip_bfloat16* __restrict__ C, int ldc,
    int nbx, int K) {
    extern __shared__ char smem[];   // 3 * 24576 bytes
    const int tid = threadIdx.x;
    const int lane = tid & 63;
    const int wave = tid >> 6;
    const int wm = wave >> 2, wn = wave & 3;
    const int fr = lane & 15, fq = lane >> 4;

    int bid = blockIdx.x;
    { const int cpx = gridDim.x >> 3; bid = (bid & 7) * cpx + (bid >> 3); }
    const int by = bid / nbx;
    const int bm = by * 128;
    const int bn = (bid - by * nbx) * 256;

    const int r0 = tid >> 2;
    const int s0 = (tid & 3) ^ ((tid >> 3) & 3);
    const __hip_bfloat16* gA0 = A + (size_t)(bm + r0) * lda + s0 * 8;
    const __hip_bfloat16* gW0 = W + (size_t)(bn + r0) * ldw + s0 * 8;
    const __hip_bfloat16* gW1 = W + (size_t)(bn + r0 + 128) * ldw + s0 * 8;
    const int dst0 = tid * 16;

    int aoff[4], boff[4];
#pragma unroll
    for (int mi = 0; mi < 4; ++mi) {
        const int row = wm * 64 + mi * 16 + fr;
        aoff[mi] = row * 64 + ((fq ^ ((row >> 1) & 3)) << 4);
    }
#pragma unroll
    for (int ni = 0; ni < 4; ++ni) {
        const int col = wn * 64 + ni * 16 + fr;
        boff[ni] = 8192 + col * 64 + ((fq ^ ((col >> 1) & 3)) << 4);
    }

    const int NT = K >> 5;
    f32x4 acc[4][4] = {};

#define STAGE_T(t)                                                    \
    do {                                                              \
        char* sb = smem + ((t) % 3) * 24576;                          \
        const int kk = (t) << 5;                                      \
        GLL16(gA0 + kk, sb + dst0);                                   \
        GLL16(gW0 + kk, sb + 8192 + dst0);                            \
        GLL16(gW1 + kk, sb + 8192 + dst0 + 8192);                     \
    } while (0)

    STAGE_T(0);
    STAGE_T(1);
    __builtin_amdgcn_sched_barrier(0);
    asm volatile("s_waitcnt vmcnt(3)" ::: "memory");
    __builtin_amdgcn_s_barrier();
    __builtin_amdgcn_sched_barrier(0);

    for (int t = 0; t < NT; ++t) {
        const char* sb = smem + (t % 3) * 24576;
        bf16x8 af[4], bg[4];
#pragma unroll
        for (int ni = 0; ni < 4; ++ni) bg[ni] = *reinterpret_cast<const bf16x8*>(sb + boff[ni]);
#pragma unroll
        for (int mi = 0; mi < 4; ++mi) af[mi] = *reinterpret_cast<const bf16x8*>(sb + aoff[mi]);

        if (t + 2 < NT) STAGE_T(t + 2);

        __builtin_amdgcn_s_setprio(1);
#pragma unroll
        for (int mi = 0; mi < 4; ++mi)
#pragma unroll
            for (int ni = 0; ni < 4; ++ni)
                acc[mi][ni] = __builtin_amdgcn_mfma_f32_16x16x32_bf16(af[mi], bg[ni], acc[mi][ni], 0, 0, 0);
        __builtin_amdgcn_s_setprio(0);

        if (t != NT - 1) {
            __builtin_amdgcn_sched_barrier(0);
            if (t + 2 < NT) asm volatile("s_waitcnt vmcnt(3)" ::: "memory");
            else            asm volatile("s_waitcnt vmcnt(0)" ::: "memory");
            __builtin_amdgcn_s_barrier();
            __builtin_amdgcn_sched_barrier(0);
        }
    }
#undef STAGE_T

#pragma unroll
    for (int ni = 0; ni < 4; ++ni) {
        const int col = bn + wn * 64 + ni * 16 + fr;
        const float bb = bias ? bias[col] : 0.0f;
#pragma unroll
        for (int mi = 0; mi < 4; ++mi) {
            const int row0 = bm + wm * 64 + mi * 16 + fq * 4;
#pragma unroll
            for (int r = 0; r < 4; ++r)
                C[(size_t)(row0 + r) * ldc + col] = __float2bfloat16(acc[mi][ni][r] + bb);
        }
    }
}

// ---------------- unified prep: cast segments + emb prefill + h init + biases, ONE launch ----------------
#define SB0 0                    // enc        (10240 blocks, flat)
#define SB1 10240                // w1a        (256, strided)
#define SB2 10496                // w1h dual   (256, strided -> wall0+wall1)
#define SB3 10752                // whh dual   (768, flat -> +262144 u4)
#define SB4 11520                // wih        (1152, flat)
#define SB5 12672                // o0         (1000, flat -> wall0 +1048576 u4)
#define SB6 13672                // o1         (1000, flat -> wall1 +1048576 u4)
#define SB7 14672                // wall0 pad zero (24)
#define SB8 14696                // wall1 pad zero (24)
#define SB9 14720                // emb prefill (3072 blocks)
#define SB10 (14720 + 3072)      // h init (1024 blocks)
#define SB11 (SB10 + 1024)       // bias0 / bias1 (2 blocks)
#define SBTOT (SB11 + 2)
__global__ __launch_bounds__(256) void prep_kernel(
    const float* __restrict__ enc, const float* __restrict__ w1,
    const float* __restrict__ whh, const float* __restrict__ wih,
    const float* __restrict__ o0, const float* __restrict__ o1,
    __hip_bfloat16* __restrict__ enc_bf, __hip_bfloat16* __restrict__ w1a_bf,
    __hip_bfloat16* __restrict__ wall0, __hip_bfloat16* __restrict__ wall1,
    __hip_bfloat16* __restrict__ wih_bf,
    const float* __restrict__ emb, const int* __restrict__ targets,
    __hip_bfloat16* __restrict__ x0, __hip_bfloat16* __restrict__ x1, __hip_bfloat16* __restrict__ x2,
    const float* __restrict__ enc_h, float* __restrict__ h, __hip_bfloat16* __restrict__ h_bf,
    const float* __restrict__ b1, const float* __restrict__ b_hh,
    const float* __restrict__ o0b, const float* __restrict__ o1b,
    float* __restrict__ bias0, float* __restrict__ bias1) {
    const int blk = blockIdx.x;
    const int tid = threadIdx.x;
    ushort4* w0u = reinterpret_cast<ushort4*>(wall0);
    ushort4* w1u = reinterpret_cast<ushort4*>(wall1);

    if (blk < SB1) {                      // enc (flat)
        const int li = blk * 1024 + tid;
        const float4* s = reinterpret_cast<const float4*>(enc);
        float4 v0 = s[li], v1 = s[li + 256], v2 = s[li + 512], v3 = s[li + 768];
        ushort4* d = reinterpret_cast<ushort4*>(enc_bf);
        d[li] = cvt4(v0); d[li + 256] = cvt4(v1); d[li + 512] = cvt4(v2); d[li + 768] = cvt4(v3);
    } else if (blk < SB2) {               // w1[:, :H] (strided)
        const int r0 = (blk - SB1) * 4;
        const float4* s = reinterpret_cast<const float4*>(w1);
        float4 v0 = s[(r0 + 0) * 512 + tid], v1 = s[(r0 + 1) * 512 + tid],
               v2 = s[(r0 + 2) * 512 + tid], v3 = s[(r0 + 3) * 512 + tid];
        ushort4* d = reinterpret_cast<ushort4*>(w1a_bf);
        const int li = r0 * 256 + tid;
        d[li] = cvt4(v0); d[li + 256] = cvt4(v1); d[li + 512] = cvt4(v2); d[li + 768] = cvt4(v3);
    } else if (blk < SB3) {               // w1[:, H:] (strided, dual write)
        const int r0 = (blk - SB2) * 4;
        const float4* s = reinterpret_cast<const float4*>(w1);
        ushort4 u0 = cvt4(s[(r0 + 0) * 512 + 256 + tid]), u1 = cvt4(s[(r0 + 1) * 512 + 256 + tid]),
                u2 = cvt4(s[(r0 + 2) * 512 + 256 + tid]), u3 = cvt4(s[(r0 + 3) * 512 + 256 + tid]);
        const int li = r0 * 256 + tid;
        w0u[li] = u0; w0u[li + 256] = u1; w0u[li + 512] = u2; w0u[li + 768] = u3;
        w1u[li] = u0; w1u[li + 256] = u1; w1u[li + 512] = u2; w1u[li + 768] = u3;
    } else if (blk < SB4) {               // whh (flat, dual write)
        const int li = (blk - SB3) * 1024 + tid;
        const float4* s = reinterpret_cast<const float4*>(whh);
        ushort4 u0 = cvt4(s[li]), u1 = cvt4(s[li + 256]), u2 = cvt4(s[li + 512]), u3 = cvt4(s[li + 768]);
        w0u[262144 + li] = u0; w0u[262144 + li + 256] = u1;
        w0u[262144 + li + 512] = u2; w0u[262144 + li + 768] = u3;
        w1u[262144 + li] = u0; w1u[262144 + li + 256] = u1;
        w1u[262144 + li + 512] = u2; w1u[262144 + li + 768] = u3;
    } else if (blk < SB5) {               // wih (flat)
        const int li = (blk - SB4) * 1024 + tid;
        const float4* s = reinterpret_cast<const float4*>(wih);
        float4 v0 = s[li], v1 = s[li + 256], v2 = s[li + 512], v3 = s[li + 768];
        ushort4* d = reinterpret_cast<ushort4*>(wih_bf);
        d[li] = cvt4(v0); d[li + 256] = cvt4(v1); d[li + 512] = cvt4(v2); d[li + 768] = cvt4(v3);
    } else if (blk < SB6) {               // o0 (flat)
        const int li = (blk - SB5) * 1024 + tid;
        const float4* s = reinterpret_cast<const float4*>(o0);
        float4 v0 = s[li], v1 = s[li + 256], v2 = s[li + 512], v3 = s[li + 768];
        w0u[1048576 + li] = cvt4(v0); w0u[1048576 + li + 256] = cvt4(v1);
        w0u[1048576 + li + 512] = cvt4(v2); w0u[1048576 + li + 768] = cvt4(v3);
    } else if (blk < SB7) {               // o1 (flat)
        const int li = (blk - SB6) * 1024 + tid;
        const float4* s = reinterpret_cast<const float4*>(o1);
        float4 v0 = s[li], v1 = s[li + 256], v2 = s[li + 512], v3 = s[li + 768];
        w1u[1048576 + li] = cvt4(v0); w1u[1048576 + li + 256] = cvt4(v1);
        w1u[1048576 + li + 512] = cvt4(v2); w1u[1048576 + li + 768] = cvt4(v3);
    } else if (blk < SB9) {               // zero pad rows
        const ushort4 z = make_ushort4(0, 0, 0, 0);
        if (blk < SB8) {
            const int li = 2072576 + (blk - SB7) * 1024 + tid;
            w0u[li] = z; w0u[li + 256] = z; w0u[li + 512] = z; w0u[li + 768] = z;
        } else {
            const int li = 2072576 + (blk - SB8) * 1024 + tid;
            w1u[li] = z; w1u[li + 256] = z; w1u[li + 512] = z; w1u[li + 768] = z;
        }
    } else if (blk < SB10) {              // emb prefill
        if (tid >= 128) return;
        const int e = blk - SB9;
        const int t = e >> 10;
        const int b = e & 1023;
        int it; __hip_bfloat16* x;
        if (t == 0) { it = 0; x = x0; }
        else if (t == 1) { it = targets[b] + 1; x = x1; }
        else { it = targets[B_SZ + b] + 36; x = x2; }
        float4 v = reinterpret_cast<const float4*>(emb + (size_t)it * DW_SZ)[tid];
        reinterpret_cast<ushort4*>(x + (size_t)b * XW)[tid] = cvt4(v);
    } else if (blk < SB11) {              // h init
        const int i = (blk - SB10) * 256 + tid;
        const float4 v = reinterpret_cast<const float4*>(enc_h)[i];
        reinterpret_cast<float4*>(h)[i] = v;
        reinterpret_cast<ushort4*>(h_bf)[i] = cvt4(v);
    } else {                              // biases
        float* bt = (blk == SB11) ? bias0 : bias1;
        const float* ob = (blk == SB11) ? o0b : o1b;
        for (int j = tid; j < NGL; j += 256) {
            float v;
            if (j < H_SZ) v = b1[j];
            else if (j < 4 * H_SZ) v = b_hh[j - H_SZ];
            else if (j < 4 * H_SZ + V_SZ) v = ob[j - 4 * H_SZ];
            else v = 0.0f;
            bt[j] = v;
        }
    }
}

// ---------------- fused: blocks [0,nattn) = attention; rest = log-softmax ----------------
__global__ __launch_bounds__(256) void attn_ls_kernel(
    const __hip_bfloat16* __restrict__ enc,
    const __hip_bfloat16* __restrict__ enc_proj,
    const __hip_bfloat16* __restrict__ hgl,    // [B][NGL]; hproj at +0, logits at +4096
    const float* __restrict__ w2,
    __hip_bfloat16* __restrict__ x,
    float* __restrict__ outp,
    int nattn) {
    const int blk = blockIdx.x;
    const int tid = threadIdx.x;
    const int lane = tid & 63, wave = tid >> 6;
    __shared__ float s_e[S_SZ];
    __shared__ float s_red[4];
    __shared__ float s_bc;

    if (blk < nattn) {
        const int b = blk;
        float hp[16], wv[16];
        const unsigned short* hgrow = reinterpret_cast<const unsigned short*>(hgl) + (size_t)b * NGL;
#pragma unroll
        for (int p = 0; p < 4; ++p) {
            const int base = p * 256 + lane * 4;
            ushort4 hu = *reinterpret_cast<const ushort4*>(hgrow + base);
            float4 wq = *reinterpret_cast<const float4*>(w2 + base);
            hp[p * 4 + 0] = bfraw2f(hu.x); hp[p * 4 + 1] = bfraw2f(hu.y);
            hp[p * 4 + 2] = bfraw2f(hu.z); hp[p * 4 + 3] = bfraw2f(hu.w);
            wv[p * 4 + 0] = wq.x; wv[p * 4 + 1] = wq.y;
            wv[p * 4 + 2] = wq.z; wv[p * 4 + 3] = wq.w;
        }

        const unsigned short* ep0 = reinterpret_cast<const unsigned short*>(enc_proj) + (size_t)b * S_SZ * H_SZ;
#pragma unroll 2
        for (int i = 0; i < 10; ++i) {
            const int s = wave + 4 * i;
            const unsigned short* row = ep0 + (size_t)s * H_SZ;
            float acc = 0.f;
#pragma unroll
            for (int p = 0; p < 4; ++p) {
                ushort4 eu = *reinterpret_cast<const ushort4*>(row + p * 256 + lane * 4);
                acc += fast_tanh(bfraw2f(eu.x) + hp[p * 4 + 0]) * wv[p * 4 + 0]
                     + fast_tanh(bfraw2f(eu.y) + hp[p * 4 + 1]) * wv[p * 4 + 1]
                     + fast_tanh(bfraw2f(eu.z) + hp[p * 4 + 2]) * wv[p * 4 + 2]
                     + fast_tanh(bfraw2f(eu.w) + hp[p * 4 + 3]) * wv[p * 4 + 3];
            }
#pragma unroll
            for (int off = 32; off > 0; off >>= 1) acc += __shfl_down(acc, off);
            if (lane == 0) s_e[s] = acc;
        }
        __syncthreads();

        float m = -1e30f;
        for (int s = 0; s < S_SZ; ++s) m = fmaxf(m, s_e[s]);
        float sum = 0.f;
        for (int s = 0; s < S_SZ; ++s) sum += __expf(s_e[s] - m);
        const float inv = 1.0f / sum;

        const ushort4* enc_b = reinterpret_cast<const ushort4*>(enc + (size_t)b * S_SZ * H_SZ);
        float4 acc = make_float4(0.f, 0.f, 0.f, 0.f);
        for (int s = 0; s < S_SZ; ++s) {
            const float a = __expf(s_e[s] - m) * inv;
            ushort4 ev = enc_b[s * 256 + tid];
            acc.x += a * bfraw2f(ev.x); acc.y += a * bfraw2f(ev.y);
            acc.z += a * bfraw2f(ev.z); acc.w += a * bfraw2f(ev.w);
        }
        reinterpret_cast<ushort4*>(x + (size_t)b * XW + DW_SZ)[tid] = cvt4(acc);
    } else {
        const int b = blk - nattn;
        const ushort4* row4 = reinterpret_cast<const ushort4*>(
            reinterpret_cast<const unsigned short*>(hgl) + (size_t)b * NGL + 4096);
        float* orow = outp + (size_t)b * V_SZ;

        float m = -1e30f;
        for (int k = tid; k < V_SZ / 4; k += 256) {
            ushort4 u = row4[k];
            m = fmaxf(m, fmaxf(fmaxf(bfraw2f(u.x), bfraw2f(u.y)), fmaxf(bfraw2f(u.z), bfraw2f(u.w))));
        }
#pragma unroll
        for (int off = 32; off > 0; off >>= 1) m = fmaxf(m, __shfl_down(m, off));
        if (lane == 0) s_red[wave] = m;
        __syncthreads();
        if (tid == 0) s_bc = fmaxf(fmaxf(s_red[0], s_red[1]), fmaxf(s_red[2], s_red[3]));
        __syncthreads();
        m = s_bc;

        float sum = 0.f;
        for (int k = tid; k < V_SZ / 4; k += 256) {
            ushort4 u = row4[k];
            sum += expf(bfraw2f(u.x) - m) + expf(bfraw2f(u.y) - m)
                 + expf(bfraw2f(u.z) - m) + expf(bfraw2f(u.w) - m);
        }
#pragma unroll
        for (int off = 32; off > 0; off >>= 1) sum += __shfl_down(sum, off);
        __syncthreads();
        if (lane == 0) s_red[wave] = sum;
        __syncthreads();
        if (tid == 0) s_bc = logf(s_red[0] + s_red[1] + s_red[2] + s_red[3]) + m;
        __syncthreads();
        const float ls = s_bc;

        for (int k = tid; k < V_SZ / 4; k += 256) {
            ushort4 u = row4[k];
            float4 o = make_float4(bfraw2f(u.x) - ls, bfraw2f(u.y) - ls,
                                   bfraw2f(u.z) - ls, bfraw2f(u.w) - ls);
            reinterpret_cast<float4*>(orow)[k] = o;
        }
    }
}

// ---------------- GRU gate combine ----------------
__global__ __launch_bounds__(256) void gru_gate_kernel(
    const __hip_bfloat16* __restrict__ gi,
    const __hip_bfloat16* __restrict__ hgl,   // gh at +H, row stride NGL
    float* __restrict__ h,
    __hip_bfloat16* __restrict__ h_bf) {
    const int idx = blockIdx.x * 256 + threadIdx.x;
    const int b = idx >> 10;
    const int j = idx & 1023;
    const unsigned short* gib = reinterpret_cast<const unsigned short*>(gi) + (size_t)b * 3 * H_SZ;
    const unsigned short* ghb = reinterpret_cast<const unsigned short*>(hgl) + (size_t)b * NGL + H_SZ;
    const float i_r = bfraw2f(gib[j]), i_z = bfraw2f(gib[H_SZ + j]), i_n = bfraw2f(gib[2 * H_SZ + j]);
    const float h_r = bfraw2f(ghb[j]), h_z = bfraw2f(ghb[H_SZ + j]), h_n = bfraw2f(ghb[2 * H_SZ + j]);
    const float r = fast_sigmoid(i_r + h_r);
    const float z = fast_sigmoid(i_z + h_z);
    const float n = fast_tanh(i_n + r * h_n);
    const float hv = (1.0f - z) * n + z * h[idx];
    h[idx] = hv;
    h_bf[idx] = __float2bfloat16(hv);
}

extern "C" void kernel_launch(void* const* d_in, const int* in_sizes, int n_in,
                              void* d_out, int out_size, void* d_ws, size_t ws_size,
                              hipStream_t stream) {
    const float* enc    = (const float*)d_in[0];
    const float* enc_h  = (const float*)d_in[1];
    const int*   tgt    = (const int*)d_in[2];
    const float* emb    = (const float*)d_in[3];
    const float* w1     = (const float*)d_in[4];
    const float* b1     = (const float*)d_in[5];
    const float* w2     = (const float*)d_in[6];
    const float* w_ih   = (const float*)d_in[7];
    const float* w_hh   = (const float*)d_in[8];
    const float* b_ih   = (const float*)d_in[9];
    const float* b_hh   = (const float*)d_in[10];
    const float* out0_w = (const float*)d_in[11];
    const float* out0_b = (const float*)d_in[12];
    const float* out1_w = (const float*)d_in[13];
    const float* out1_b = (const float*)d_in[14];
    float* out = (float*)d_out;

    char* wp = (char*)d_ws;
    auto carve = [&](size_t bytes) { char* p = wp; wp += (bytes + 255) & ~(size_t)255; return p; };
    __hip_bfloat16* enc_bf  = (__hip_bfloat16*)carve((size_t)B_SZ * S_SZ * H_SZ * 2);
    __hip_bfloat16* encp_bf = (__hip_bfloat16*)carve((size_t)B_SZ * S_SZ * H_SZ * 2);
    __hip_bfloat16* w1a_bf  = (__hip_bfloat16*)carve((size_t)H_SZ * H_SZ * 2);
    __hip_bfloat16* wall0   = (__hip_bfloat16*)carve((size_t)NGL * H_SZ * 2);   // [w1h; whh; o0; pad]
    __hip_bfloat16* wall1   = (__hip_bfloat16*)carve((size_t)NGL * H_SZ * 2);   // [w1h; whh; o1; pad]
    __hip_bfloat16* wih_bf  = (__hip_bfloat16*)carve((size_t)3 * H_SZ * XW * 2);
    float*          bias0   = (float*)carve((size_t)NGL * 4);
    float*          bias1   = (float*)carve((size_t)NGL * 4);
    float*          h       = (float*)carve((size_t)B_SZ * H_SZ * 4);
    __hip_bfloat16* h_bf    = (__hip_bfloat16*)carve((size_t)B_SZ * H_SZ * 2);
    __hip_bfloat16* hgl     = (__hip_bfloat16*)carve((size_t)B_SZ * NGL * 2);   // [hproj|gh|logits|pad]
    __hip_bfloat16* x_bf[3];
    for (int t = 0; t < 3; ++t) x_bf[t] = (__hip_bfloat16*)carve((size_t)B_SZ * XW * 2);
    __hip_bfloat16* gi_bf   = (__hip_bfloat16*)carve((size_t)B_SZ * 3 * H_SZ * 2);

    // --- prep: 1 launch ---
    prep_kernel<<<SBTOT, 256, 0, stream>>>(enc, w1, w_hh, w_ih, out0_w, out1_w,
                                           enc_bf, w1a_bf, wall0, wall1, wih_bf,
                                           emb, tgt, x_bf[0], x_bf[1], x_bf[2],
                                           enc_h, h, h_bf, b1, b_hh, out0_b, out1_b,
                                           bias0, bias1);

    // enc_proj = enc @ w1[:, :H].T   (M=40960, N=1024, K=1024) -- v1 (256 thr, measured best here)
    gemm_bt_pipe128_v1<<<(B_SZ * S_SZ / 128) * (H_SZ / 256), 256, 3 * 24576, stream>>>(
        enc_bf, H_SZ, w1a_bf, H_SZ, nullptr, encp_bf, H_SZ, H_SZ / 256, H_SZ);

    // hg(0): first 4096 cols of hgl = h0 @ wcat.T + [b1|b_hh]
    gemm_bt_pipe128_v2<<<(B_SZ / 128) * 16, 512, 3 * 24576, stream>>>(
        h_bf, H_SZ, wall0, H_SZ, bias0, hgl, NGL, 16, H_SZ);

    // attn(0) standalone
    attn_ls_kernel<<<B_SZ, 256, 0, stream>>>(enc_bf, encp_bf, hgl, w2, x_bf[0], out, B_SZ);

    for (int t = 0; t < 3; ++t) {
        // gi = x @ w_ih.T + b_ih   (M=1024, N=3072, K=1536)
        gemm_bt_pipe128_v2<<<(B_SZ / 128) * 12, 512, 3 * 24576, stream>>>(
            x_bf[t], XW, wih_bf, XW, b_ih, gi_bf, 3 * H_SZ, 12, XW);

        gru_gate_kernel<<<(B_SZ * H_SZ) / 256, 256, 0, stream>>>(gi_bf, hgl, h, h_bf);

        // hgl = h @ wall_t.T + bias_t : [hg(t+1) | logits(t)]
        // logits weights: t==0 -> o0 (wall0), t==1 -> o1 (wall1), t==2 -> o0 (wall0)
        if (t == 0) {
            gemm_bt_pipe128_v2<<<(B_SZ / 128) * 32, 512, 3 * 24576, stream>>>(
                h_bf, H_SZ, wall0, H_SZ, bias0, hgl, NGL, 32, H_SZ);
        } else if (t == 1) {
            gemm_bt_pipe128_v2<<<(B_SZ / 128) * 32, 512, 3 * 24576, stream>>>(
                h_bf, H_SZ, wall1, H_SZ, bias1, hgl, NGL, 32, H_SZ);
        } else {
            gemm_bt_pipe128_v2<<<(B_SZ / 128) * 16, 512, 3 * 24576, stream>>>(
                h_bf, H_SZ, wall0 + (size_t)4 * H_SZ * H_SZ, H_SZ, bias0 + 4 * H_SZ,
                hgl + 4 * H_SZ, NGL, 16, H_SZ);
        }

        // fused: log-softmax(t) [+ attention(t+1) when t<2]
        float* outp = out + (size_t)t * B_SZ * V_SZ;
        if (t < 2) {
            attn_ls_kernel<<<2 * B_SZ, 256, 0, stream>>>(enc_bf, encp_bf, hgl, w2, x_bf[t + 1],
                                                         outp, B_SZ);
        } else {
            attn_ls_kernel<<<B_SZ, 256, 0, stream>>>(enc_bf, encp_bf, hgl, w2, x_bf[0],
                                                     outp, 0);
        }
    }
}

// Round 16
// 479.331 us; speedup vs baseline: 1.2185x; 1.0222x over previous
//
#include <hip/hip_runtime.h>
#include <hip/hip_bf16.h>
#include <math.h>

#define B_SZ 1024
#define S_SZ 40
#define H_SZ 1024
#define DW_SZ 512
#define V_SZ 4000
#define XW (DW_SZ + H_SZ)      // 1536
#define NGL 8192               // hgl row: [hproj(1024) | gh(3072) | logits(4000) | pad(96)]

typedef __bf16 bf16x8 __attribute__((ext_vector_type(8)));
typedef float f32x4 __attribute__((ext_vector_type(4)));
typedef unsigned short u16x8 __attribute__((ext_vector_type(8)));

__device__ __forceinline__ float fast_tanh(float x) {
    return 1.0f - 2.0f / (1.0f + __expf(2.0f * x));
}
__device__ __forceinline__ float fast_sigmoid(float x) {
    return 1.0f / (1.0f + __expf(-x));
}
__device__ __forceinline__ float bfraw2f(unsigned short u) {
    return __uint_as_float(((unsigned)u) << 16);
}
__device__ __forceinline__ ushort4 cvt4(float4 v) {
    union { ushort4 u; __hip_bfloat16 h[4]; } o;
    o.h[0] = __float2bfloat16(v.x); o.h[1] = __float2bfloat16(v.y);
    o.h[2] = __float2bfloat16(v.z); o.h[3] = __float2bfloat16(v.w);
    return o.u;
}
__device__ __forceinline__ u16x8 pack8(float4 a, float4 b) {
    union { u16x8 v; ushort4 h[2]; } o;
    o.h[0] = cvt4(a); o.h[1] = cvt4(b);
    return o.v;
}

#define GLL16(gp, lp)                                                                \
    __builtin_amdgcn_global_load_lds((const __attribute__((address_space(1))) void*)(gp), \
                                     (__attribute__((address_space(3))) void*)(lp), 16, 0, 0)

// ---- weight-cast tail blocks (appended to the enc_proj grid): blk in [0, 4224) ----
__device__ void cast_tail_block(int blk, int tid,
                                const float* __restrict__ w1, const float* __restrict__ whh,
                                const float* __restrict__ wih, const float* __restrict__ o0,
                                const float* __restrict__ o1,
                                __hip_bfloat16* __restrict__ wall0,
                                __hip_bfloat16* __restrict__ wall1,
                                __hip_bfloat16* __restrict__ wih_bf) {
    ushort4* w0u = reinterpret_cast<ushort4*>(wall0);
    ushort4* w1u = reinterpret_cast<ushort4*>(wall1);
    if (blk < 256) {                      // w1[:, H:] strided, dual write
        const int r0 = blk * 4;
        const float4* s = reinterpret_cast<const float4*>(w1);
        ushort4 u0 = cvt4(s[(r0 + 0) * 512 + 256 + tid]), u1 = cvt4(s[(r0 + 1) * 512 + 256 + tid]),
                u2 = cvt4(s[(r0 + 2) * 512 + 256 + tid]), u3 = cvt4(s[(r0 + 3) * 512 + 256 + tid]);
        const int li = r0 * 256 + tid;
        w0u[li] = u0; w0u[li + 256] = u1; w0u[li + 512] = u2; w0u[li + 768] = u3;
        w1u[li] = u0; w1u[li + 256] = u1; w1u[li + 512] = u2; w1u[li + 768] = u3;
    } else if (blk < 1024) {              // whh flat, dual write (768 blocks)
        const int li = (blk - 256) * 1024 + tid;
        const float4* s = reinterpret_cast<const float4*>(whh);
        ushort4 u0 = cvt4(s[li]), u1 = cvt4(s[li + 256]), u2 = cvt4(s[li + 512]), u3 = cvt4(s[li + 768]);
        w0u[262144 + li] = u0; w0u[262144 + li + 256] = u1;
        w0u[262144 + li + 512] = u2; w0u[262144 + li + 768] = u3;
        w1u[262144 + li] = u0; w1u[262144 + li + 256] = u1;
        w1u[262144 + li + 512] = u2; w1u[262144 + li + 768] = u3;
    } else if (blk < 2176) {              // wih flat (1152)
        const int li = (blk - 1024) * 1024 + tid;
        const float4* s = reinterpret_cast<const float4*>(wih);
        float4 v0 = s[li], v1 = s[li + 256], v2 = s[li + 512], v3 = s[li + 768];
        ushort4* d = reinterpret_cast<ushort4*>(wih_bf);
        d[li] = cvt4(v0); d[li + 256] = cvt4(v1); d[li + 512] = cvt4(v2); d[li + 768] = cvt4(v3);
    } else if (blk < 3176) {              // o0 (1000)
        const int li = (blk - 2176) * 1024 + tid;
        const float4* s = reinterpret_cast<const float4*>(o0);
        float4 v0 = s[li], v1 = s[li + 256], v2 = s[li + 512], v3 = s[li + 768];
        w0u[1048576 + li] = cvt4(v0); w0u[1048576 + li + 256] = cvt4(v1);
        w0u[1048576 + li + 512] = cvt4(v2); w0u[1048576 + li + 768] = cvt4(v3);
    } else if (blk < 4176) {              // o1 (1000)
        const int li = (blk - 3176) * 1024 + tid;
        const float4* s = reinterpret_cast<const float4*>(o1);
        float4 v0 = s[li], v1 = s[li + 256], v2 = s[li + 512], v3 = s[li + 768];
        w1u[1048576 + li] = cvt4(v0); w1u[1048576 + li + 256] = cvt4(v1);
        w1u[1048576 + li + 512] = cvt4(v2); w1u[1048576 + li + 768] = cvt4(v3);
    } else {                              // zero pad rows (24 + 24)
        const ushort4 z = make_ushort4(0, 0, 0, 0);
        if (blk < 4200) {
            const int li = 2072576 + (blk - 4176) * 1024 + tid;
            w0u[li] = z; w0u[li + 256] = z; w0u[li + 512] = z; w0u[li + 768] = z;
        } else {
            const int li = 2072576 + (blk - 4200) * 1024 + tid;
            w1u[li] = z; w1u[li + 256] = z; w1u[li + 512] = z; w1u[li + 768] = z;
        }
    }
}

// ========== enc_proj GEMM (v1 128x256, proven) + appended weight-cast blocks ==========
// Blocks [0, gemm_nb): GEMM (XCD-swizzled over gemm_nb). Blocks >= gemm_nb: weight cast.
// The 320 GEMM blocks fill all 512 CU slots first; cast blocks overlap in spare slots/BW.
__global__ __launch_bounds__(256, 2) void gemm_enc_cast(
    const __hip_bfloat16* __restrict__ A, int lda,
    const __hip_bfloat16* __restrict__ W, int ldw,
    __hip_bfloat16* __restrict__ C, int ldc,
    int nbx, int K, int gemm_nb,
    const float* __restrict__ w1, const float* __restrict__ whh,
    const float* __restrict__ wih, const float* __restrict__ o0,
    const float* __restrict__ o1,
    __hip_bfloat16* __restrict__ wall0, __hip_bfloat16* __restrict__ wall1,
    __hip_bfloat16* __restrict__ wih_bf) {
    extern __shared__ char smem[];   // 3 * 24576 bytes (GEMM blocks only)
    const int tid = threadIdx.x;

    if ((int)blockIdx.x >= gemm_nb) {
        cast_tail_block(blockIdx.x - gemm_nb, tid, w1, whh, wih, o0, o1, wall0, wall1, wih_bf);
        return;
    }

    const int lane = tid & 63;
    const int wave = tid >> 6;
    const int wm = wave >> 1, wn = wave & 1;
    const int fr = lane & 15, fq = lane >> 4;

    int bid = blockIdx.x;
    { const int cpx = gemm_nb >> 3; bid = (bid & 7) * cpx + (bid >> 3); }  // XCD swizzle
    const int by = bid / nbx;
    const int bm = by * 128;
    const int bn = (bid - by * nbx) * 256;

    const int r0 = tid >> 2;
    const int s0 = (tid & 3) ^ ((tid >> 3) & 3);
    const __hip_bfloat16* gA0 = A + (size_t)(bm + r0) * lda + s0 * 8;
    const __hip_bfloat16* gA1 = A + (size_t)(bm + r0 + 64) * lda + s0 * 8;
    const __hip_bfloat16* gW0 = W + (size_t)(bn + r0) * ldw + s0 * 8;
    const __hip_bfloat16* gW1 = W + (size_t)(bn + r0 + 64) * ldw + s0 * 8;
    const __hip_bfloat16* gW2 = W + (size_t)(bn + r0 + 128) * ldw + s0 * 8;
    const __hip_bfloat16* gW3 = W + (size_t)(bn + r0 + 192) * ldw + s0 * 8;
    const int dst0 = tid * 16;

    int aoff[4], boff[8];
#pragma unroll
    for (int mi = 0; mi < 4; ++mi) {
        const int row = wm * 64 + mi * 16 + fr;
        aoff[mi] = row * 64 + ((fq ^ ((row >> 1) & 3)) << 4);
    }
#pragma unroll
    for (int ni = 0; ni < 8; ++ni) {
        const int col = wn * 128 + ni * 16 + fr;
        boff[ni] = 8192 + col * 64 + ((fq ^ ((col >> 1) & 3)) << 4);
    }

    const int NT = K >> 5;
    f32x4 acc[4][8] = {};

#define STAGE_T(t)                                                    \
    do {                                                              \
        char* sb = smem + ((t) % 3) * 24576;                          \
        const int kk = (t) << 5;                                      \
        GLL16(gA0 + kk, sb + dst0);                                   \
        GLL16(gA1 + kk, sb + dst0 + 4096);                            \
        GLL16(gW0 + kk, sb + 8192 + dst0);                            \
        GLL16(gW1 + kk, sb + 8192 + dst0 + 4096);                     \
        GLL16(gW2 + kk, sb + 8192 + dst0 + 8192);                     \
        GLL16(gW3 + kk, sb + 8192 + dst0 + 12288);                    \
    } while (0)

    STAGE_T(0);
    STAGE_T(1);
    __builtin_amdgcn_sched_barrier(0);
    asm volatile("s_waitcnt vmcnt(6)" ::: "memory");
    __builtin_amdgcn_s_barrier();
    __builtin_amdgcn_sched_barrier(0);

    for (int t = 0; t < NT; ++t) {
        const char* sb = smem + (t % 3) * 24576;
        bf16x8 af[4], bg[8];
#pragma unroll
        for (int ni = 0; ni < 8; ++ni) bg[ni] = *reinterpret_cast<const bf16x8*>(sb + boff[ni]);
#pragma unroll
        for (int mi = 0; mi < 4; ++mi) af[mi] = *reinterpret_cast<const bf16x8*>(sb + aoff[mi]);

        if (t + 2 < NT) STAGE_T(t + 2);

        __builtin_amdgcn_s_setprio(1);
#pragma unroll
        for (int mi = 0; mi < 4; ++mi)
#pragma unroll
            for (int ni = 0; ni < 8; ++ni)
                acc[mi][ni] = __builtin_amdgcn_mfma_f32_16x16x32_bf16(af[mi], bg[ni], acc[mi][ni], 0, 0, 0);
        __builtin_amdgcn_s_setprio(0);

        if (t != NT - 1) {
            __builtin_amdgcn_sched_barrier(0);
            if (t + 2 < NT) asm volatile("s_waitcnt vmcnt(6)" ::: "memory");
            else            asm volatile("s_waitcnt vmcnt(0)" ::: "memory");
            __builtin_amdgcn_s_barrier();
            __builtin_amdgcn_sched_barrier(0);
        }
    }
#undef STAGE_T

#pragma unroll
    for (int ni = 0; ni < 8; ++ni) {
        const int col = bn + wn * 128 + ni * 16 + fr;
#pragma unroll
        for (int mi = 0; mi < 4; ++mi) {
            const int row0 = bm + wm * 64 + mi * 16 + fq * 4;
#pragma unroll
            for (int r = 0; r < 4; ++r)
                C[(size_t)(row0 + r) * ldc + col] = __float2bfloat16(acc[mi][ni][r]);
        }
    }
}

// ========== v2: 128x256 tile, 512 threads (8 waves, 64x64 wave-tile) — per-step GEMMs ==========
__global__ __launch_bounds__(512, 2) void gemm_bt_pipe128_v2(
    const __hip_bfloat16* __restrict__ A, int lda,
    const __hip_bfloat16* __restrict__ W, int ldw,
    const float* __restrict__ bias,
    __hip_bfloat16* __restrict__ C, int ldc,
    int nbx, int K) {
    extern __shared__ char smem[];   // 3 * 24576 bytes
    const int tid = threadIdx.x;
    const int lane = tid & 63;
    const int wave = tid >> 6;
    const int wm = wave >> 2, wn = wave & 3;
    const int fr = lane & 15, fq = lane >> 4;

    int bid = blockIdx.x;
    { const int cpx = gridDim.x >> 3; bid = (bid & 7) * cpx + (bid >> 3); }
    const int by = bid / nbx;
    const int bm = by * 128;
    const int bn = (bid - by * nbx) * 256;

    const int r0 = tid >> 2;
    const int s0 = (tid & 3) ^ ((tid >> 3) & 3);
    const __hip_bfloat16* gA0 = A + (size_t)(bm + r0) * lda + s0 * 8;
    const __hip_bfloat16* gW0 = W + (size_t)(bn + r0) * ldw + s0 * 8;
    const __hip_bfloat16* gW1 = W + (size_t)(bn + r0 + 128) * ldw + s0 * 8;
    const int dst0 = tid * 16;

    int aoff[4], boff[4];
#pragma unroll
    for (int mi = 0; mi < 4; ++mi) {
        const int row = wm * 64 + mi * 16 + fr;
        aoff[mi] = row * 64 + ((fq ^ ((row >> 1) & 3)) << 4);
    }
#pragma unroll
    for (int ni = 0; ni < 4; ++ni) {
        const int col = wn * 64 + ni * 16 + fr;
        boff[ni] = 8192 + col * 64 + ((fq ^ ((col >> 1) & 3)) << 4);
    }

    const int NT = K >> 5;
    f32x4 acc[4][4] = {};

#define STAGE_T(t)                                                    \
    do {                                                              \
        char* sb = smem + ((t) % 3) * 24576;                          \
        const int kk = (t) << 5;                                      \
        GLL16(gA0 + kk, sb + dst0);                                   \
        GLL16(gW0 + kk, sb + 8192 + dst0);                            \
        GLL16(gW1 + kk, sb + 8192 + dst0 + 8192);                     \
    } while (0)

    STAGE_T(0);
    STAGE_T(1);
    __builtin_amdgcn_sched_barrier(0);
    asm volatile("s_waitcnt vmcnt(3)" ::: "memory");
    __builtin_amdgcn_s_barrier();
    __builtin_amdgcn_sched_barrier(0);

    for (int t = 0; t < NT; ++t) {
        const char* sb = smem + (t % 3) * 24576;
        bf16x8 af[4], bg[4];
#pragma unroll
        for (int ni = 0; ni < 4; ++ni) bg[ni] = *reinterpret_cast<const bf16x8*>(sb + boff[ni]);
#pragma unroll
        for (int mi = 0; mi < 4; ++mi) af[mi] = *reinterpret_cast<const bf16x8*>(sb + aoff[mi]);

        if (t + 2 < NT) STAGE_T(t + 2);

        __builtin_amdgcn_s_setprio(1);
#pragma unroll
        for (int mi = 0; mi < 4; ++mi)
#pragma unroll
            for (int ni = 0; ni < 4; ++ni)
                acc[mi][ni] = __builtin_amdgcn_mfma_f32_16x16x32_bf16(af[mi], bg[ni], acc[mi][ni], 0, 0, 0);
        __builtin_amdgcn_s_setprio(0);

        if (t != NT - 1) {
            __builtin_amdgcn_sched_barrier(0);
            if (t + 2 < NT) asm volatile("s_waitcnt vmcnt(3)" ::: "memory");
            else            asm volatile("s_waitcnt vmcnt(0)" ::: "memory");
            __builtin_amdgcn_s_barrier();
            __builtin_amdgcn_sched_barrier(0);
        }
    }
#undef STAGE_T

#pragma unroll
    for (int ni = 0; ni < 4; ++ni) {
        const int col = bn + wn * 64 + ni * 16 + fr;
        const float bb = bias ? bias[col] : 0.0f;
#pragma unroll
        for (int mi = 0; mi < 4; ++mi) {
            const int row0 = bm + wm * 64 + mi * 16 + fq * 4;
#pragma unroll
            for (int r = 0; r < 4; ++r)
                C[(size_t)(row0 + r) * ldc + col] = __float2bfloat16(acc[mi][ni][r] + bb);
        }
    }
}

// ---------------- prep_a: enc cast (16B stores) + w1a + emb + h + biases ----------------
#define PA_ENC 10240            // enc: 1024 f4 per block, ushort8 stores
#define PA_W1A (PA_ENC + 256)
#define PA_EMB (PA_W1A + 3072)
#define PA_H   (PA_EMB + 1024)
#define PA_TOT (PA_H + 2)
__global__ __launch_bounds__(256) void prep_a_kernel(
    const float* __restrict__ enc, const float* __restrict__ w1,
    __hip_bfloat16* __restrict__ enc_bf, __hip_bfloat16* __restrict__ w1a_bf,
    const float* __restrict__ emb, const int* __restrict__ targets,
    __hip_bfloat16* __restrict__ x0, __hip_bfloat16* __restrict__ x1, __hip_bfloat16* __restrict__ x2,
    const float* __restrict__ enc_h, float* __restrict__ h, __hip_bfloat16* __restrict__ h_bf,
    const float* __restrict__ b1, const float* __restrict__ b_hh,
    const float* __restrict__ o0b, const float* __restrict__ o1b,
    float* __restrict__ bias0, float* __restrict__ bias1) {
    const int blk = blockIdx.x;
    const int tid = threadIdx.x;

    if (blk < PA_ENC) {                   // enc: 1024 f4; thread does 2 ushort8 units (16B stores)
        const float4* s = reinterpret_cast<const float4*>(enc);
        u16x8* d = reinterpret_cast<u16x8*>(enc_bf);
        const int f0 = blk * 1024 + tid * 2;          // pair 0
        const int f1 = f0 + 512;                      // pair 1
        float4 a0 = s[f0], a1 = s[f0 + 1];
        float4 b0 = s[f1], b1v = s[f1 + 1];
        d[blk * 512 + tid] = pack8(a0, a1);
        d[blk * 512 + 256 + tid] = pack8(b0, b1v);
    } else if (blk < PA_W1A) {            // w1[:, :H] strided
        const int r0 = (blk - PA_ENC) * 4;
        const float4* s = reinterpret_cast<const float4*>(w1);
        float4 v0 = s[(r0 + 0) * 512 + tid], v1 = s[(r0 + 1) * 512 + tid],
               v2 = s[(r0 + 2) * 512 + tid], v3 = s[(r0 + 3) * 512 + tid];
        ushort4* d = reinterpret_cast<ushort4*>(w1a_bf);
        const int li = r0 * 256 + tid;
        d[li] = cvt4(v0); d[li + 256] = cvt4(v1); d[li + 512] = cvt4(v2); d[li + 768] = cvt4(v3);
    } else if (blk < PA_EMB) {            // emb prefill
        if (tid >= 128) return;
        const int e = blk - PA_W1A;
        const int t = e >> 10;
        const int b = e & 1023;
        int it; __hip_bfloat16* x;
        if (t == 0) { it = 0; x = x0; }
        else if (t == 1) { it = targets[b] + 1; x = x1; }
        else { it = targets[B_SZ + b] + 36; x = x2; }
        float4 v = reinterpret_cast<const float4*>(emb + (size_t)it * DW_SZ)[tid];
        reinterpret_cast<ushort4*>(x + (size_t)b * XW)[tid] = cvt4(v);
    } else if (blk < PA_H) {              // h init
        const int i = (blk - PA_EMB) * 256 + tid;
        const float4 v = reinterpret_cast<const float4*>(enc_h)[i];
        reinterpret_cast<float4*>(h)[i] = v;
        reinterpret_cast<ushort4*>(h_bf)[i] = cvt4(v);
    } else {                              // biases
        float* bt = (blk == PA_H) ? bias0 : bias1;
        const float* ob = (blk == PA_H) ? o0b : o1b;
        for (int j = tid; j < NGL; j += 256) {
            float v;
            if (j < H_SZ) v = b1[j];
            else if (j < 4 * H_SZ) v = b_hh[j - H_SZ];
            else if (j < 4 * H_SZ + V_SZ) v = ob[j - 4 * H_SZ];
            else v = 0.0f;
            bt[j] = v;
        }
    }
}

// ---------------- fused: blocks [0,nattn) = attention; rest = log-softmax ----------------
__global__ __launch_bounds__(256) void attn_ls_kernel(
    const __hip_bfloat16* __restrict__ enc,
    const __hip_bfloat16* __restrict__ enc_proj,
    const __hip_bfloat16* __restrict__ hgl,    // [B][NGL]; hproj at +0, logits at +4096
    const float* __restrict__ w2,
    __hip_bfloat16* __restrict__ x,
    float* __restrict__ outp,
    int nattn) {
    const int blk = blockIdx.x;
    const int tid = threadIdx.x;
    const int lane = tid & 63, wave = tid >> 6;
    __shared__ float s_e[S_SZ];
    __shared__ float s_red[4];
    __shared__ float s_bc;

    if (blk < nattn) {
        const int b = blk;
        float hp[16], wv[16];
        const unsigned short* hgrow = reinterpret_cast<const unsigned short*>(hgl) + (size_t)b * NGL;
#pragma unroll
        for (int p = 0; p < 4; ++p) {
            const int base = p * 256 + lane * 4;
            ushort4 hu = *reinterpret_cast<const ushort4*>(hgrow + base);
            float4 wq = *reinterpret_cast<const float4*>(w2 + base);
            hp[p * 4 + 0] = bfraw2f(hu.x); hp[p * 4 + 1] = bfraw2f(hu.y);
            hp[p * 4 + 2] = bfraw2f(hu.z); hp[p * 4 + 3] = bfraw2f(hu.w);
            wv[p * 4 + 0] = wq.x; wv[p * 4 + 1] = wq.y;
            wv[p * 4 + 2] = wq.z; wv[p * 4 + 3] = wq.w;
        }

        const unsigned short* ep0 = reinterpret_cast<const unsigned short*>(enc_proj) + (size_t)b * S_SZ * H_SZ;
#pragma unroll 2
        for (int i = 0; i < 10; ++i) {
            const int s = wave + 4 * i;
            const unsigned short* row = ep0 + (size_t)s * H_SZ;
            float acc = 0.f;
#pragma unroll
            for (int p = 0; p < 4; ++p) {
                ushort4 eu = *reinterpret_cast<const ushort4*>(row + p * 256 + lane * 4);
                acc += fast_tanh(bfraw2f(eu.x) + hp[p * 4 + 0]) * wv[p * 4 + 0]
                     + fast_tanh(bfraw2f(eu.y) + hp[p * 4 + 1]) * wv[p * 4 + 1]
                     + fast_tanh(bfraw2f(eu.z) + hp[p * 4 + 2]) * wv[p * 4 + 2]
                     + fast_tanh(bfraw2f(eu.w) + hp[p * 4 + 3]) * wv[p * 4 + 3];
            }
#pragma unroll
            for (int off = 32; off > 0; off >>= 1) acc += __shfl_down(acc, off);
            if (lane == 0) s_e[s] = acc;
        }
        __syncthreads();

        float m = -1e30f;
        for (int s = 0; s < S_SZ; ++s) m = fmaxf(m, s_e[s]);
        float sum = 0.f;
        for (int s = 0; s < S_SZ; ++s) sum += __expf(s_e[s] - m);
        const float inv = 1.0f / sum;

        const ushort4* enc_b = reinterpret_cast<const ushort4*>(enc + (size_t)b * S_SZ * H_SZ);
        float4 acc = make_float4(0.f, 0.f, 0.f, 0.f);
        for (int s = 0; s < S_SZ; ++s) {
            const float a = __expf(s_e[s] - m) * inv;
            ushort4 ev = enc_b[s * 256 + tid];
            acc.x += a * bfraw2f(ev.x); acc.y += a * bfraw2f(ev.y);
            acc.z += a * bfraw2f(ev.z); acc.w += a * bfraw2f(ev.w);
        }
        reinterpret_cast<ushort4*>(x + (size_t)b * XW + DW_SZ)[tid] = cvt4(acc);
    } else {
        const int b = blk - nattn;
        const ushort4* row4 = reinterpret_cast<const ushort4*>(
            reinterpret_cast<const unsigned short*>(hgl) + (size_t)b * NGL + 4096);
        float* orow = outp + (size_t)b * V_SZ;

        float m = -1e30f;
        for (int k = tid; k < V_SZ / 4; k += 256) {
            ushort4 u = row4[k];
            m = fmaxf(m, fmaxf(fmaxf(bfraw2f(u.x), bfraw2f(u.y)), fmaxf(bfraw2f(u.z), bfraw2f(u.w))));
        }
#pragma unroll
        for (int off = 32; off > 0; off >>= 1) m = fmaxf(m, __shfl_down(m, off));
        if (lane == 0) s_red[wave] = m;
        __syncthreads();
        if (tid == 0) s_bc = fmaxf(fmaxf(s_red[0], s_red[1]), fmaxf(s_red[2], s_red[3]));
        __syncthreads();
        m = s_bc;

        float sum = 0.f;
        for (int k = tid; k < V_SZ / 4; k += 256) {
            ushort4 u = row4[k];
            sum += expf(bfraw2f(u.x) - m) + expf(bfraw2f(u.y) - m)
                 + expf(bfraw2f(u.z) - m) + expf(bfraw2f(u.w) - m);
        }
#pragma unroll
        for (int off = 32; off > 0; off >>= 1) sum += __shfl_down(sum, off);
        __syncthreads();
        if (lane == 0) s_red[wave] = sum;
        __syncthreads();
        if (tid == 0) s_bc = logf(s_red[0] + s_red[1] + s_red[2] + s_red[3]) + m;
        __syncthreads();
        const float ls = s_bc;

        for (int k = tid; k < V_SZ / 4; k += 256) {
            ushort4 u = row4[k];
            float4 o = make_float4(bfraw2f(u.x) - ls, bfraw2f(u.y) - ls,
                                   bfraw2f(u.z) - ls, bfraw2f(u.w) - ls);
            reinterpret_cast<float4*>(orow)[k] = o;
        }
    }
}

// ---------------- GRU gate combine ----------------
__global__ __launch_bounds__(256) void gru_gate_kernel(
    const __hip_bfloat16* __restrict__ gi,
    const __hip_bfloat16* __restrict__ hgl,   // gh at +H, row stride NGL
    float* __restrict__ h,
    __hip_bfloat16* __restrict__ h_bf) {
    const int idx = blockIdx.x * 256 + threadIdx.x;
    const int b = idx >> 10;
    const int j = idx & 1023;
    const unsigned short* gib = reinterpret_cast<const unsigned short*>(gi) + (size_t)b * 3 * H_SZ;
    const unsigned short* ghb = reinterpret_cast<const unsigned short*>(hgl) + (size_t)b * NGL + H_SZ;
    const float i_r = bfraw2f(gib[j]), i_z = bfraw2f(gib[H_SZ + j]), i_n = bfraw2f(gib[2 * H_SZ + j]);
    const float h_r = bfraw2f(ghb[j]), h_z = bfraw2f(ghb[H_SZ + j]), h_n = bfraw2f(ghb[2 * H_SZ + j]);
    const float r = fast_sigmoid(i_r + h_r);
    const float z = fast_sigmoid(i_z + h_z);
    const float n = fast_tanh(i_n + r * h_n);
    const float hv = (1.0f - z) * n + z * h[idx];
    h[idx] = hv;
    h_bf[idx] = __float2bfloat16(hv);
}

extern "C" void kernel_launch(void* const* d_in, const int* in_sizes, int n_in,
                              void* d_out, int out_size, void* d_ws, size_t ws_size,
                              hipStream_t stream) {
    const float* enc    = (const float*)d_in[0];
    const float* enc_h  = (const float*)d_in[1];
    const int*   tgt    = (const int*)d_in[2];
    const float* emb    = (const float*)d_in[3];
    const float* w1     = (const float*)d_in[4];
    const float* b1     = (const float*)d_in[5];
    const float* w2     = (const float*)d_in[6];
    const float* w_ih   = (const float*)d_in[7];
    const float* w_hh   = (const float*)d_in[8];
    const float* b_ih   = (const float*)d_in[9];
    const float* b_hh   = (const float*)d_in[10];
    const float* out0_w = (const float*)d_in[11];
    const float* out0_b = (const float*)d_in[12];
    const float* out1_w = (const float*)d_in[13];
    const float* out1_b = (const float*)d_in[14];
    float* out = (float*)d_out;

    char* wp = (char*)d_ws;
    auto carve = [&](size_t bytes) { char* p = wp; wp += (bytes + 255) & ~(size_t)255; return p; };
    __hip_bfloat16* enc_bf  = (__hip_bfloat16*)carve((size_t)B_SZ * S_SZ * H_SZ * 2);
    __hip_bfloat16* encp_bf = (__hip_bfloat16*)carve((size_t)B_SZ * S_SZ * H_SZ * 2);
    __hip_bfloat16* w1a_bf  = (__hip_bfloat16*)carve((size_t)H_SZ * H_SZ * 2);
    __hip_bfloat16* wall0   = (__hip_bfloat16*)carve((size_t)NGL * H_SZ * 2);   // [w1h; whh; o0; pad]
    __hip_bfloat16* wall1   = (__hip_bfloat16*)carve((size_t)NGL * H_SZ * 2);   // [w1h; whh; o1; pad]
    __hip_bfloat16* wih_bf  = (__hip_bfloat16*)carve((size_t)3 * H_SZ * XW * 2);
    float*          bias0   = (float*)carve((size_t)NGL * 4);
    float*          bias1   = (float*)carve((size_t)NGL * 4);
    float*          h       = (float*)carve((size_t)B_SZ * H_SZ * 4);
    __hip_bfloat16* h_bf    = (__hip_bfloat16*)carve((size_t)B_SZ * H_SZ * 2);
    __hip_bfloat16* hgl     = (__hip_bfloat16*)carve((size_t)B_SZ * NGL * 2);   // [hproj|gh|logits|pad]
    __hip_bfloat16* x_bf[3];
    for (int t = 0; t < 3; ++t) x_bf[t] = (__hip_bfloat16*)carve((size_t)B_SZ * XW * 2);
    __hip_bfloat16* gi_bf   = (__hip_bfloat16*)carve((size_t)B_SZ * 3 * H_SZ * 2);

    // --- prep_a: enc cast (16B stores) + w1a + emb + h + biases ---
    prep_a_kernel<<<PA_TOT, 256, 0, stream>>>(enc, w1, enc_bf, w1a_bf,
                                              emb, tgt, x_bf[0], x_bf[1], x_bf[2],
                                              enc_h, h, h_bf, b1, b_hh, out0_b, out1_b,
                                              bias0, bias1);

    // --- enc_proj GEMM (320 blocks) + weight-cast tail (4224 blocks), overlapped ---
    const int gemm_nb = (B_SZ * S_SZ / 128) * (H_SZ / 256);   // 320
    gemm_enc_cast<<<gemm_nb + 4224, 256, 3 * 24576, stream>>>(
        enc_bf, H_SZ, w1a_bf, H_SZ, encp_bf, H_SZ, H_SZ / 256, H_SZ, gemm_nb,
        w1, w_hh, w_ih, out0_w, out1_w, wall0, wall1, wih_bf);

    // hg(0): first 4096 cols of hgl = h0 @ wcat.T + [b1|b_hh]
    gemm_bt_pipe128_v2<<<(B_SZ / 128) * 16, 512, 3 * 24576, stream>>>(
        h_bf, H_SZ, wall0, H_SZ, bias0, hgl, NGL, 16, H_SZ);

    // attn(0) standalone
    attn_ls_kernel<<<B_SZ, 256, 0, stream>>>(enc_bf, encp_bf, hgl, w2, x_bf[0], out, B_SZ);

    for (int t = 0; t < 3; ++t) {
        // gi = x @ w_ih.T + b_ih   (M=1024, N=3072, K=1536)
        gemm_bt_pipe128_v2<<<(B_SZ / 128) * 12, 512, 3 * 24576, stream>>>(
            x_bf[t], XW, wih_bf, XW, b_ih, gi_bf, 3 * H_SZ, 12, XW);

        gru_gate_kernel<<<(B_SZ * H_SZ) / 256, 256, 0, stream>>>(gi_bf, hgl, h, h_bf);

        // hgl = h @ wall_t.T + bias_t : [hg(t+1) | logits(t)]
        // logits weights: t==0 -> o0 (wall0), t==1 -> o1 (wall1), t==2 -> o0 (wall0)
        if (t == 0) {
            gemm_bt_pipe128_v2<<<(B_SZ / 128) * 32, 512, 3 * 24576, stream>>>(
                h_bf, H_SZ, wall0, H_SZ, bias0, hgl, NGL, 32, H_SZ);
        } else if (t == 1) {
            gemm_bt_pipe128_v2<<<(B_SZ / 128) * 32, 512, 3 * 24576, stream>>>(
                h_bf, H_SZ, wall1, H_SZ, bias1, hgl, NGL, 32, H_SZ);
        } else {
            gemm_bt_pipe128_v2<<<(B_SZ / 128) * 16, 512, 3 * 24576, stream>>>(
                h_bf, H_SZ, wall0 + (size_t)4 * H_SZ * H_SZ, H_SZ, bias0 + 4 * H_SZ,
                hgl + 4 * H_SZ, NGL, 16, H_SZ);
        }

        // fused: log-softmax(t) [+ attention(t+1) when t<2]
        float* outp = out + (size_t)t * B_SZ * V_SZ;
        if (t < 2) {
            attn_ls_kernel<<<2 * B_SZ, 256, 0, stream>>>(enc_bf, encp_bf, hgl, w2, x_bf[t + 1],
                                                         outp, B_SZ);
        } else {
            attn_ls_kernel<<<B_SZ, 256, 0, stream>>>(enc_bf, encp_bf, hgl, w2, x_bf[0],
                                                     outp, 0);
        }
    }
}